// Round 1
// 1434.659 us; speedup vs baseline: 1.0864x; 1.0864x over previous
//
#include <hip/hip_runtime.h>
#include <hip/hip_bf16.h>
#include <cmath>
#include <cstdint>

#define B_ 4
#define N_ 2048
#define M_ 512
#define H_ 12
#define D_ 64
#define DIM_ 768
#define QKV_ 2304
#define SCALE_ 0.125f
#define NEG_ -1e9f
#define TEMP_ 24.0f

typedef __attribute__((ext_vector_type(8))) short bf16x8;
typedef __attribute__((ext_vector_type(4))) float f32x4;

__device__ __forceinline__ short f2bf(float f) {
  union { float f; unsigned u; } v; v.f = f;
  unsigned r = v.u + 0x7fffu + ((v.u >> 16) & 1u);
  return (short)(r >> 16);
}
__device__ __forceinline__ float bf2f(short s) {
  union { unsigned u; float f; } v; v.u = ((unsigned)(unsigned short)s) << 16;
  return v.f;
}
#define MFMA16(a, b, c) __builtin_amdgcn_mfma_f32_16x16x32_bf16(a, b, c, 0, 0, 0)

// ---------------------------------------------------------------------------
// Transpose + split W [K][Ncols] fp32 -> Wt_h/Wt_l [Ncols][K] bf16.
// ---------------------------------------------------------------------------
__global__ __launch_bounds__(256) void wsplit_t(
    const float* __restrict__ W, int K, int Ncols,
    short* __restrict__ Wt_h, short* __restrict__ Wt_l) {
  __shared__ float t[32][33];
  const int n0 = blockIdx.x * 32, k0 = blockIdx.y * 32;
  const int tid = threadIdx.x;
  for (int e = tid; e < 1024; e += 256) {
    int r = e >> 5, c = e & 31;
    t[r][c] = W[(size_t)(k0 + r) * Ncols + n0 + c];
  }
  __syncthreads();
  for (int e = tid; e < 1024; e += 256) {
    int r = e >> 5, c = e & 31;  // r = n-local, c = k-local
    float f = t[c][r];
    short hi = f2bf(f);
    short lo = f2bf(f - bf2f(hi));
    size_t o = (size_t)(n0 + r) * K + k0 + c;
    Wt_h[o] = hi; Wt_l[o] = lo;
  }
}

// ---------------------------------------------------------------------------
// Pack int32 mask [B,H,N,M] -> bitmask [B,H,N,M/32] via wave ballot.
// ---------------------------------------------------------------------------
__global__ __launch_bounds__(256) void mask_pack(
    const int* __restrict__ mask, unsigned* __restrict__ pm) {
  const size_t total = (size_t)B_ * H_ * N_ * M_;
  const size_t stride = (size_t)gridDim.x * blockDim.x;
  const int lane = threadIdx.x & 63;
  for (size_t i = (size_t)blockIdx.x * blockDim.x + threadIdx.x; i < total;
       i += stride) {
    unsigned long long bal = __ballot(mask[i] != 0);
    if (lane == 0) *(unsigned long long*)(pm + (i >> 5)) = bal;
  }
}

// ---------------------------------------------------------------------------
// QKV GEMM (MFMA, split-bf16): A[rows,768] fp32 @ Wt^T -> q/k hi/lo bf16
// [B,H,rows,64] and v transposed bf16 [B,H,64,rows]. Tile 128x128, 4 waves.
// ---------------------------------------------------------------------------
__global__ __launch_bounds__(256) void qkv_mfma(
    const float* __restrict__ A, const short* __restrict__ Wth,
    const short* __restrict__ Wtl, int rowsPerB, int totalRows,
    short* __restrict__ qh, short* __restrict__ ql,
    short* __restrict__ kh, short* __restrict__ kl,
    short* __restrict__ vt) {
  __shared__ __align__(16) short As_h[128 * 40], As_l[128 * 40];
  __shared__ __align__(16) short Bs_h[128 * 40], Bs_l[128 * 40];
  const int r0 = blockIdx.y * 128, c0 = blockIdx.x * 128;
  const int tid = threadIdx.x;
  const int w = tid >> 6, ln = tid & 63, q = ln >> 4, l15 = ln & 15;
  const int wM = (w & 1) * 64, wN = (w >> 1) * 64;
  const f32x4 z = {0.f, 0.f, 0.f, 0.f};
  f32x4 acc[4][4];
  for (int i = 0; i < 4; i++)
    for (int j = 0; j < 4; j++) acc[i][j] = z;
  for (int k0 = 0; k0 < DIM_; k0 += 32) {
    for (int e = tid; e < 1024; e += 256) {  // A: 128 rows x 8 float4
      int row = e >> 3, c = e & 7;
      int ar = r0 + row; if (ar >= totalRows) ar = totalRows - 1;
      float4 f = *(const float4*)(A + (size_t)ar * DIM_ + k0 + c * 4);
      short h0 = f2bf(f.x), h1 = f2bf(f.y), h2 = f2bf(f.z), h3 = f2bf(f.w);
      short l0 = f2bf(f.x - bf2f(h0)), l1 = f2bf(f.y - bf2f(h1));
      short l2 = f2bf(f.z - bf2f(h2)), l3 = f2bf(f.w - bf2f(h3));
      int o = row * 40 + c * 4;
      *(short4*)(As_h + o) = make_short4(h0, h1, h2, h3);
      *(short4*)(As_l + o) = make_short4(l0, l1, l2, l3);
    }
    for (int e = tid; e < 512; e += 256) {  // B: 128 n-rows x 4 uint4
      int row = e >> 2, c = e & 3;
      size_t go = (size_t)(c0 + row) * DIM_ + k0 + c * 8;
      int o = row * 40 + c * 8;
      *(uint4*)(Bs_h + o) = *(const uint4*)(Wth + go);
      *(uint4*)(Bs_l + o) = *(const uint4*)(Wtl + go);
    }
    __syncthreads();
    bf16x8 ah[4], al[4], bhf[4], blf[4];
    for (int mt = 0; mt < 4; mt++) {
      int o = (wM + mt * 16 + l15) * 40 + q * 8;
      ah[mt] = *(const bf16x8*)(As_h + o);
      al[mt] = *(const bf16x8*)(As_l + o);
    }
    for (int nt = 0; nt < 4; nt++) {
      int o = (wN + nt * 16 + l15) * 40 + q * 8;
      bhf[nt] = *(const bf16x8*)(Bs_h + o);
      blf[nt] = *(const bf16x8*)(Bs_l + o);
    }
    for (int mt = 0; mt < 4; mt++)
      for (int nt = 0; nt < 4; nt++) {
        f32x4 c = acc[mt][nt];
        c = MFMA16(ah[mt], bhf[nt], c);
        c = MFMA16(ah[mt], blf[nt], c);
        c = MFMA16(al[mt], bhf[nt], c);
        acc[mt][nt] = c;
      }
    __syncthreads();
  }
  for (int mt = 0; mt < 4; mt++)
    for (int nt = 0; nt < 4; nt++)
      for (int r = 0; r < 4; r++) {
        int gr = r0 + wM + mt * 16 + q * 4 + r;
        if (gr >= totalRows) continue;
        int gc = c0 + wN + nt * 16 + l15;
        int which = gc / DIM_;
        int rem = gc - which * DIM_;
        int hh = rem >> 6, d = rem & 63;
        int b = gr / rowsPerB, n = gr - b * rowsPerB;
        float v = acc[mt][nt][r];
        short hi = f2bf(v);
        if (which == 2) {
          vt[(((size_t)b * H_ + hh) * 64 + d) * rowsPerB + n] = hi;
        } else {
          short lo = f2bf(v - bf2f(hi));
          size_t o = (((size_t)b * H_ + hh) * rowsPerB + n) * 64 + d;
          if (which == 0) { qh[o] = hi; ql[o] = lo; }
          else           { kh[o] = hi; kl[o] = lo; }
        }
      }
}

// ---------------------------------------------------------------------------
// Output projection (MFMA, split-bf16): A hi/lo bf16 [rows,768] @ Wot^T + b.
// ---------------------------------------------------------------------------
__global__ __launch_bounds__(256) void proj_mfma(
    const short* __restrict__ Ahp, const short* __restrict__ Alp,
    const short* __restrict__ Bth, const short* __restrict__ Btl,
    const float* __restrict__ bias, float* __restrict__ C, int totalRows) {
  __shared__ __align__(16) short As_h[128 * 40], As_l[128 * 40];
  __shared__ __align__(16) short Bs_h[128 * 40], Bs_l[128 * 40];
  const int r0 = blockIdx.y * 128, c0 = blockIdx.x * 128;
  const int tid = threadIdx.x;
  const int w = tid >> 6, ln = tid & 63, q = ln >> 4, l15 = ln & 15;
  const int wM = (w & 1) * 64, wN = (w >> 1) * 64;
  const f32x4 z = {0.f, 0.f, 0.f, 0.f};
  f32x4 acc[4][4];
  for (int i = 0; i < 4; i++)
    for (int j = 0; j < 4; j++) acc[i][j] = z;
  for (int k0 = 0; k0 < DIM_; k0 += 32) {
    for (int e = tid; e < 512; e += 256) {
      int row = e >> 2, c = e & 3;
      int ar = r0 + row; if (ar >= totalRows) ar = totalRows - 1;
      size_t ga = (size_t)ar * DIM_ + k0 + c * 8;
      size_t gb = (size_t)(c0 + row) * DIM_ + k0 + c * 8;
      int o = row * 40 + c * 8;
      *(uint4*)(As_h + o) = *(const uint4*)(Ahp + ga);
      *(uint4*)(As_l + o) = *(const uint4*)(Alp + ga);
      *(uint4*)(Bs_h + o) = *(const uint4*)(Bth + gb);
      *(uint4*)(Bs_l + o) = *(const uint4*)(Btl + gb);
    }
    __syncthreads();
    bf16x8 ah[4], al[4], bhf[4], blf[4];
    for (int mt = 0; mt < 4; mt++) {
      int o = (wM + mt * 16 + l15) * 40 + q * 8;
      ah[mt] = *(const bf16x8*)(As_h + o);
      al[mt] = *(const bf16x8*)(As_l + o);
    }
    for (int nt = 0; nt < 4; nt++) {
      int o = (wN + nt * 16 + l15) * 40 + q * 8;
      bhf[nt] = *(const bf16x8*)(Bs_h + o);
      blf[nt] = *(const bf16x8*)(Bs_l + o);
    }
    for (int mt = 0; mt < 4; mt++)
      for (int nt = 0; nt < 4; nt++) {
        f32x4 c = acc[mt][nt];
        c = MFMA16(ah[mt], bhf[nt], c);
        c = MFMA16(ah[mt], blf[nt], c);
        c = MFMA16(al[mt], bhf[nt], c);
        acc[mt][nt] = c;
      }
    __syncthreads();
  }
  for (int mt = 0; mt < 4; mt++)
    for (int nt = 0; nt < 4; nt++)
      for (int r = 0; r < 4; r++) {
        int gr = r0 + wM + mt * 16 + q * 4 + r;
        if (gr >= totalRows) continue;
        int gc = c0 + wN + nt * 16 + l15;
        C[(size_t)gr * DIM_ + gc] = acc[mt][nt][r] + bias[gc];
      }
}

// ---------------------------------------------------------------------------
// Branch 1 (MFMA): per (b,h,32 n-rows), 512 threads / 8 waves.
// QK^T split-bf16, two softmaxes over M=512, out3 write, P(hi/lo) @ V.
// Scores in LDS (col-XOR-swizzled); P overlays scores via register staging.
// krd prefetched into registers across the stats phase.
// ---------------------------------------------------------------------------
__global__ __launch_bounds__(512, 4) void branch1_mfma(
    const short* __restrict__ tqh, const short* __restrict__ tql,
    const short* __restrict__ kkh, const short* __restrict__ kkl,
    const short* __restrict__ kvt, const float* __restrict__ krd,
    const unsigned* __restrict__ pm, float* __restrict__ out3,
    short* __restrict__ amh, short* __restrict__ aml) {
  __shared__ __align__(16) float sc[32 * 520];  // 66560 B, aliased by P2h/P2l
  __shared__ unsigned mskw[512];                // 32 rows x 16 words
  __shared__ float rowM[32], inv1[32], inv2[32];
  short* P2h = (short*)sc;          // [32][520]
  short* P2l = P2h + 32 * 520;
  const int b = blockIdx.z, h = blockIdx.y, n0 = blockIdx.x * 32;
  const size_t bhi = (size_t)b * H_ + h;
  const int tid = threadIdx.x;
  const int w = tid >> 6, ln = tid & 63, q = ln >> 4, l15 = ln & 15;
  const float* krd0 = krd + bhi * M_ * N_;
  mskw[tid] = pm[(bhi * N_ + n0) * 16 + tid];
  // ---- QK^T: 32n x 512m, wave w -> ct in [4w, 4w+4) ----
  {
    bf16x8 ah[2][2], al[2][2];
    for (int mt = 0; mt < 2; mt++) {
      const short* ap = tqh + ((bhi * N_ + n0 + mt * 16 + l15) * D_ + q * 8);
      const short* ap2 = tql + ((bhi * N_ + n0 + mt * 16 + l15) * D_ + q * 8);
      ah[mt][0] = *(const bf16x8*)(ap);
      ah[mt][1] = *(const bf16x8*)(ap + 32);
      al[mt][0] = *(const bf16x8*)(ap2);
      al[mt][1] = *(const bf16x8*)(ap2 + 32);
    }
    for (int t = 0; t < 4; t++) {
      int ct = w * 4 + t;
      const short* bp = kkh + ((bhi * M_ + ct * 16 + l15) * D_ + q * 8);
      const short* bp2 = kkl + ((bhi * M_ + ct * 16 + l15) * D_ + q * 8);
      bf16x8 bh0 = *(const bf16x8*)(bp);
      bf16x8 bh1 = *(const bf16x8*)(bp + 32);
      bf16x8 bl0 = *(const bf16x8*)(bp2);
      bf16x8 bl1 = *(const bf16x8*)(bp2 + 32);
      for (int mt = 0; mt < 2; mt++) {
        f32x4 a = {0.f, 0.f, 0.f, 0.f};
        a = MFMA16(ah[mt][0], bh0, a); a = MFMA16(ah[mt][1], bh1, a);
        a = MFMA16(ah[mt][0], bl0, a); a = MFMA16(ah[mt][1], bl1, a);
        a = MFMA16(al[mt][0], bh0, a); a = MFMA16(al[mt][1], bh1, a);
        for (int r = 0; r < 4; r++) {
          int row = mt * 16 + q * 4 + r;
          sc[row * 520 + ((ct * 16 + l15) ^ ((row >> 2) & 7))] = a[r];
        }
      }
    }
  }
  // ---- prefetch krd for P-build (latency hides under stats phase) ----
  const int pi = tid & 31, pg = tid >> 5;
  float kr[32];
#pragma unroll
  for (int t = 0; t < 32; t++)
    kr[t] = krd0[(size_t)(pg * 32 + t) * N_ + n0 + pi];
  __syncthreads();
  // ---- mask + scale + row stats (both denominators) ----
  {
    int i = tid >> 4, jl = tid & 15;
    int sw = (i >> 2) & 7;
    float* scr = sc + i * 520;
    const unsigned* mrow = mskw + i * 16;
    float mx = -INFINITY;
    for (int j = jl; j < M_; j += 16) {
      float dv = scr[j ^ sw];
      dv = ((mrow[j >> 5] >> (j & 31)) & 1) ? NEG_ : dv * SCALE_;
      scr[j ^ sw] = dv;
      mx = fmaxf(mx, dv);
    }
    for (int o = 8; o >= 1; o >>= 1) mx = fmaxf(mx, __shfl_xor(mx, o, 16));
    float s1 = 0.f, s2 = 0.f;
    for (int j = jl; j < M_; j += 16) {
      float dv = scr[j ^ sw] - mx;
      s1 += __expf(dv * TEMP_);
      s2 += __expf(dv);
    }
    for (int o = 8; o >= 1; o >>= 1) {
      s1 += __shfl_xor(s1, o, 16);
      s2 += __shfl_xor(s2, o, 16);
    }
    if (jl == 0) { rowM[i] = mx; inv1[i] = 1.f / s1; inv2[i] = 1.f / s2; }
  }
  __syncthreads();
  // ---- P build: out3 write + P2 hi/lo (overlay sc via register staging) ----
  {
    float rv[32];
    int sw2 = (pi >> 2) & 7;
#pragma unroll
    for (int t = 0; t < 32; t++)
      rv[t] = sc[pi * 520 + ((pg * 32 + t) ^ sw2)];
    __syncthreads();
    float mx = rowM[pi], v1 = inv1[pi], v2 = inv2[pi];
    float* o3 = out3 + bhi * M_ * N_ + n0 + pi;
#pragma unroll 4
    for (int t = 0; t < 32; t += 2) {
      int j = pg * 32 + t;
      float dv0 = rv[t] - mx, dv1 = rv[t + 1] - mx;
      o3[(size_t)j * N_] = __expf(dv0 * TEMP_) * v1 * kr[t];
      o3[(size_t)(j + 1) * N_] = __expf(dv1 * TEMP_) * v1 * kr[t + 1];
      float p0 = __expf(dv0) * v2 * kr[t];
      float p1 = __expf(dv1) * v2 * kr[t + 1];
      short h0 = f2bf(p0), h1 = f2bf(p1);
      short lo0 = f2bf(p0 - bf2f(h0)), lo1 = f2bf(p1 - bf2f(h1));
      *(short2*)(P2h + pi * 520 + j) = make_short2(h0, h1);
      *(short2*)(P2l + pi * 520 + j) = make_short2(lo0, lo1);
    }
  }
  __syncthreads();
  // ---- PV: wave w -> (n-half, d-chunk) ----
  {
    const int dc = w & 3, nh = w >> 2;
    f32x4 o0 = {0.f, 0.f, 0.f, 0.f}, o1 = {0.f, 0.f, 0.f, 0.f};
    const short* vbase = kvt + ((bhi * 64 + dc * 16 + l15) * (size_t)M_ + q * 8);
    const short* ph = P2h + (nh * 16 + l15) * 520 + q * 8;
    const short* pl = P2l + (nh * 16 + l15) * 520 + q * 8;
    for (int kc = 0; kc < 16; kc += 2) {
      bf16x8 pa0 = *(const bf16x8*)(ph + kc * 32);
      bf16x8 pl0 = *(const bf16x8*)(pl + kc * 32);
      bf16x8 bv0 = *(const bf16x8*)(vbase + kc * 32);
      o0 = MFMA16(pa0, bv0, o0);
      o0 = MFMA16(pl0, bv0, o0);
      bf16x8 pa1 = *(const bf16x8*)(ph + (kc + 1) * 32);
      bf16x8 pl1 = *(const bf16x8*)(pl + (kc + 1) * 32);
      bf16x8 bv1 = *(const bf16x8*)(vbase + (kc + 1) * 32);
      o1 = MFMA16(pa1, bv1, o1);
      o1 = MFMA16(pl1, bv1, o1);
    }
    o0 += o1;
    for (int r = 0; r < 4; r++) {
      float v = o0[r];
      short hi = f2bf(v), lo = f2bf(v - bf2f(hi));
      size_t o = ((size_t)b * N_ + n0 + nh * 16 + q * 4 + r) * DIM_ +
                 h * 64 + dc * 16 + l15;
      amh[o] = hi; aml[o] = lo;
    }
  }
}

// ---------------------------------------------------------------------------
// Branch 2 (MFMA, flash): per (b,h,32 m-rows), loop n-chunks of 128.
// Mask comes from the packed bitmask: one word per n row.
// ---------------------------------------------------------------------------
__global__ __launch_bounds__(256) void branch2_mfma(
    const short* __restrict__ kqh, const short* __restrict__ kql,
    const short* __restrict__ tkh, const short* __restrict__ tkl,
    const short* __restrict__ tvt, const float* __restrict__ krd,
    const unsigned* __restrict__ pm, short* __restrict__ kmh,
    short* __restrict__ kml) {
  __shared__ __align__(16) float sc[32 * 136];  // 17408 B, aliased by P2h/P2l
  __shared__ unsigned mskw[128];
  __shared__ float rowM[32], rowL[32], alph[32];
  short* P2h = (short*)sc;          // [32][136]
  short* P2l = P2h + 32 * 136;
  const int b = blockIdx.z, h = blockIdx.y, m0 = blockIdx.x * 32;
  const size_t bhi = (size_t)b * H_ + h;
  const int tid = threadIdx.x;
  const int w = tid >> 6, ln = tid & 63, q = ln >> 4, l15 = ln & 15;
  const float* krd0 = krd + (bhi * M_ + m0) * N_;
  const int mword = m0 >> 5;
  bf16x8 Ah[2][2], Al[2][2];
  for (int mt = 0; mt < 2; mt++)
    for (int kc = 0; kc < 2; kc++) {
      size_t o = (bhi * M_ + m0 + mt * 16 + l15) * D_ + kc * 32 + q * 8;
      Ah[mt][kc] = *(const bf16x8*)(kqh + o);
      Al[mt][kc] = *(const bf16x8*)(kql + o);
    }
  if (tid < 32) { rowM[tid] = -INFINITY; rowL[tid] = 0.f; }
  const f32x4 z = {0.f, 0.f, 0.f, 0.f};
  f32x4 oa[2]; oa[0] = z; oa[1] = z;
  __syncthreads();
  for (int n0 = 0; n0 < N_; n0 += 128) {
    if (tid < 128) mskw[tid] = pm[(bhi * N_ + n0 + tid) * 16 + mword];
    for (int t = 0; t < 2; t++) {  // QK: wave w -> ct = 2w+t
      int ct = w * 2 + t;
      const short* bp = tkh + ((bhi * N_ + n0 + ct * 16 + l15) * D_ + q * 8);
      const short* bp2 = tkl + ((bhi * N_ + n0 + ct * 16 + l15) * D_ + q * 8);
      bf16x8 bh0 = *(const bf16x8*)(bp), bh1 = *(const bf16x8*)(bp + 32);
      bf16x8 bl0 = *(const bf16x8*)(bp2), bl1 = *(const bf16x8*)(bp2 + 32);
      for (int mt = 0; mt < 2; mt++) {
        f32x4 a = {0.f, 0.f, 0.f, 0.f};
        a = MFMA16(Ah[mt][0], bh0, a); a = MFMA16(Ah[mt][1], bh1, a);
        a = MFMA16(Ah[mt][0], bl0, a); a = MFMA16(Ah[mt][1], bl1, a);
        a = MFMA16(Al[mt][0], bh0, a); a = MFMA16(Al[mt][1], bh1, a);
        for (int r = 0; r < 4; r++)
          sc[(mt * 16 + q * 4 + r) * 136 + ct * 16 + l15] = a[r];
      }
    }
    __syncthreads();
    {  // online softmax: 8 threads/row
      int i = tid >> 3, jl = tid & 7;
      float mx = -INFINITY;
      for (int j = jl; j < 128; j += 8) {
        float s = sc[i * 136 + j];
        s = ((mskw[j] >> i) & 1) ? NEG_ : s * SCALE_;
        sc[i * 136 + j] = s;
        mx = fmaxf(mx, s);
      }
      for (int o = 4; o >= 1; o >>= 1) mx = fmaxf(mx, __shfl_xor(mx, o, 8));
      float mold = rowM[i];
      float mnew = fmaxf(mold, mx);
      float sum = 0.f;
      for (int j = jl; j < 128; j += 8) {
        float p = __expf(sc[i * 136 + j] - mnew);
        sc[i * 136 + j] = p;
        sum += p;
      }
      for (int o = 4; o >= 1; o >>= 1) sum += __shfl_xor(sum, o, 8);
      if (jl == 0) {
        float al = (mold == -INFINITY) ? 0.f : __expf(mold - mnew);
        alph[i] = al;
        rowL[i] = rowL[i] * al + sum;
        rowM[i] = mnew;
      }
    }
    __syncthreads();
    {  // P2 = p * krd, hi/lo (overlay sc via register staging)
      float rv[16];
      const int j = tid & 127;
      for (int t = 0; t < 16; t++) rv[t] = sc[((tid >> 7) + 2 * t) * 136 + j];
      __syncthreads();
      for (int t = 0; t < 16; t++) {
        int i = (tid >> 7) + 2 * t;
        float p2 = rv[t] * krd0[(size_t)i * N_ + n0 + j];
        short hi = f2bf(p2), lo = f2bf(p2 - bf2f(hi));
        P2h[i * 136 + j] = hi;
        P2l[i * 136 + j] = lo;
      }
    }
    __syncthreads();
    {  // PV accumulate, wave w -> dc = w
      for (int mt = 0; mt < 2; mt++) {
        f32x4 t = oa[mt];
        for (int r = 0; r < 4; r++) t[r] *= alph[mt * 16 + q * 4 + r];
        for (int kc = 0; kc < 4; kc++) {
          bf16x8 pa = *(const bf16x8*)(P2h + (mt * 16 + l15) * 136 + kc * 32 + q * 8);
          bf16x8 pl = *(const bf16x8*)(P2l + (mt * 16 + l15) * 136 + kc * 32 + q * 8);
          bf16x8 bv = *(const bf16x8*)(tvt + ((bhi * 64 + w * 16 + l15) * (size_t)N_ + n0 + kc * 32 + q * 8));
          t = MFMA16(pa, bv, t);
          t = MFMA16(pl, bv, t);
        }
        oa[mt] = t;
      }
    }
    __syncthreads();
  }
  for (int mt = 0; mt < 2; mt++)
    for (int r = 0; r < 4; r++) {
      int row = mt * 16 + q * 4 + r;
      float v = oa[mt][r] / rowL[row];
      short hi = f2bf(v), lo = f2bf(v - bf2f(hi));
      size_t o = ((size_t)b * M_ + m0 + row) * DIM_ + h * 64 + w * 16 + l15;
      kmh[o] = hi; kml[o] = lo;
    }
}

// ---------------------------------------------------------------------------
// Branch 3: cluster query per (b,h), vector math from hi/lo inputs.
// ---------------------------------------------------------------------------
__global__ __launch_bounds__(256) void branch3_k(
    const short* __restrict__ cqh, const short* __restrict__ cql,
    const short* __restrict__ kkh, const short* __restrict__ kkl,
    const short* __restrict__ kvt, const int* __restrict__ mask,
    short* __restrict__ cmh, short* __restrict__ cml) {
  const int h = blockIdx.x, b = blockIdx.y;
  __shared__ float qv[64];
  __shared__ float p[512];
  __shared__ float wr1[4], wr2[4];
  __shared__ float ored[4][64];
  const size_t bhi = (size_t)b * H_ + h;
  const int tid = threadIdx.x;
  if (tid < 64) qv[tid] = bf2f(cqh[bhi * 64 + tid]) + bf2f(cql[bhi * 64 + tid]);
  __syncthreads();
  const int* mask0 = mask + bhi * N_ * M_;  // row n = 0
  for (int j = tid; j < 512; j += 256) {
    float acc = 0;
    for (int kk = 0; kk < 64; kk++)
      acc += qv[kk] * (bf2f(kkh[(bhi * M_ + j) * 64 + kk]) +
                       bf2f(kkl[(bhi * M_ + j) * 64 + kk]));
    acc *= SCALE_;
    if (mask0[j]) acc = NEG_;
    p[j] = acc;
  }
  __syncthreads();
  float mx = fmaxf(p[tid], p[tid + 256]);
  for (int o = 32; o >= 1; o >>= 1) mx = fmaxf(mx, __shfl_xor(mx, o, 64));
  if ((tid & 63) == 0) wr1[tid >> 6] = mx;
  __syncthreads();
  mx = fmaxf(fmaxf(wr1[0], wr1[1]), fmaxf(wr1[2], wr1[3]));
  float e0 = __expf(p[tid] - mx), e1 = __expf(p[tid + 256] - mx);
  float s = e0 + e1;
  for (int o = 32; o >= 1; o >>= 1) s += __shfl_xor(s, o, 64);
  p[tid] = e0; p[tid + 256] = e1;
  if ((tid & 63) == 0) wr2[tid >> 6] = s;
  __syncthreads();
  float invS = 1.f / (wr2[0] + wr2[1] + wr2[2] + wr2[3]);
  int dd = tid & 63, gg = tid >> 6;
  float o = 0;
  for (int j = gg; j < 512; j += 4)
    o += p[j] * bf2f(kvt[(bhi * 64 + dd) * (size_t)M_ + j]);
  ored[gg][dd] = o;
  __syncthreads();
  if (gg == 0) {
    float r = (ored[0][dd] + ored[1][dd] + ored[2][dd] + ored[3][dd]) * invS;
    short hi = f2bf(r), lo = f2bf(r - bf2f(hi));
    cmh[(size_t)b * DIM_ + h * 64 + dd] = hi;
    cml[(size_t)b * DIM_ + h * 64 + dd] = lo;
  }
}

// ---------------------------------------------------------------------------
extern "C" void kernel_launch(void* const* d_in, const int* in_sizes, int n_in,
                              void* d_out, int out_size, void* d_ws,
                              size_t ws_size, hipStream_t stream) {
  const float* x = (const float*)d_in[0];
  const float* kx = (const float*)d_in[1];
  const float* krd = (const float*)d_in[2];
  const float* clst = (const float*)d_in[3];
  const int* mask = (const int*)d_in[4];
  const float* Wqkv = (const float*)d_in[5];
  const float* Wout = (const float*)d_in[6];
  const float* bout = (const float*)d_in[7];

  short* p = (short*)d_ws;
  auto alloc = [&](size_t n) { short* r = p; p += n; return r; };
  short* Wq_h = alloc(2304ull * 768); short* Wq_l = alloc(2304ull * 768);
  short* Wo_h = alloc(768ull * 768);  short* Wo_l = alloc(768ull * 768);
  short* tq_h = alloc(6291456); short* tq_l = alloc(6291456);
  short* tk_h = alloc(6291456); short* tk_l = alloc(6291456);
  short* tv_t = alloc(6291456);
  short* kq_h = alloc(1572864); short* kq_l = alloc(1572864);
  short* kk_h = alloc(1572864); short* kk_l = alloc(1572864);
  short* kv_t = alloc(1572864);
  short* cq_h = alloc(3072); short* cq_l = alloc(3072);
  short* ck_h = alloc(3072); short* ck_l = alloc(3072);
  short* cv_t = alloc(3072);
  short* am_h = alloc(6291456); short* am_l = alloc(6291456);
  short* km_h = alloc(1572864); short* km_l = alloc(1572864);
  short* cm_h = alloc(3072); short* cm_l = alloc(3072);

  float* out0 = (float*)d_out;        // [B,N,768]
  float* out1 = out0 + 6291456;       // [B,M,768]
  float* out2 = out1 + 1572864;       // [B,1,768]
  float* out3 = out2 + 3072;          // [B,H,M,N]

  wsplit_t<<<dim3(72, 24), 256, 0, stream>>>(Wqkv, DIM_, QKV_, Wq_h, Wq_l);
  wsplit_t<<<dim3(24, 24), 256, 0, stream>>>(Wout, DIM_, DIM_, Wo_h, Wo_l);

  qkv_mfma<<<dim3(18, 64), 256, 0, stream>>>(x, Wq_h, Wq_l, N_, B_ * N_,
                                             tq_h, tq_l, tk_h, tk_l, tv_t);
  qkv_mfma<<<dim3(18, 16), 256, 0, stream>>>(kx, Wq_h, Wq_l, M_, B_ * M_,
                                             kq_h, kq_l, kk_h, kk_l, kv_t);
  qkv_mfma<<<dim3(18, 1), 256, 0, stream>>>(clst, Wq_h, Wq_l, 1, B_,
                                            cq_h, cq_l, ck_h, ck_l, cv_t);

  // Wq_h/Wq_l are dead after the qkv GEMMs; reuse their space for the packed
  // mask (needs 6.29 MB < 7.08 MB). Stream-ordered, so this is safe.
  unsigned* pmask = (unsigned*)Wq_h;
  mask_pack<<<dim3(2048), 256, 0, stream>>>(mask, pmask);

  branch1_mfma<<<dim3(N_ / 32, H_, B_), 512, 0, stream>>>(
      tq_h, tq_l, kk_h, kk_l, kv_t, krd, pmask, out3, am_h, am_l);
  branch2_mfma<<<dim3(M_ / 32, H_, B_), 256, 0, stream>>>(
      kq_h, kq_l, tk_h, tk_l, tv_t, krd, pmask, km_h, km_l);
  branch3_k<<<dim3(H_, B_), 256, 0, stream>>>(cq_h, cq_l, kk_h, kk_l, kv_t,
                                              mask, cm_h, cm_l);

  proj_mfma<<<dim3(6, 64), 256, 0, stream>>>(am_h, am_l, Wo_h, Wo_l, bout,
                                             out0, B_ * N_);
  proj_mfma<<<dim3(6, 16), 256, 0, stream>>>(km_h, km_l, Wo_h, Wo_l, bout,
                                             out1, B_ * M_);
  proj_mfma<<<dim3(6, 1), 256, 0, stream>>>(cm_h, cm_l, Wo_h, Wo_l, bout,
                                            out2, B_);
}

// Round 2
// 1233.709 us; speedup vs baseline: 1.2633x; 1.1629x over previous
//
#include <hip/hip_runtime.h>
#include <hip/hip_bf16.h>
#include <cmath>
#include <cstdint>

#define B_ 4
#define N_ 2048
#define M_ 512
#define H_ 12
#define D_ 64
#define DIM_ 768
#define QKV_ 2304
#define SCALE_ 0.125f
#define NEG_ -1e9f
#define TEMP_ 24.0f

typedef __attribute__((ext_vector_type(8))) short bf16x8;
typedef __attribute__((ext_vector_type(4))) float f32x4;

__device__ __forceinline__ short f2bf(float f) {
  union { float f; unsigned u; } v; v.f = f;
  unsigned r = v.u + 0x7fffu + ((v.u >> 16) & 1u);
  return (short)(r >> 16);
}
__device__ __forceinline__ float bf2f(short s) {
  union { unsigned u; float f; } v; v.u = ((unsigned)(unsigned short)s) << 16;
  return v.f;
}
#define MFMA16(a, b, c) __builtin_amdgcn_mfma_f32_16x16x32_bf16(a, b, c, 0, 0, 0)

// Bijective XCD-chunked swizzle (m204): consecutive remapped ids stay on one
// XCD so tiles sharing an A row-panel hit the same L2.
__device__ __forceinline__ int xcd_swizzle(int orig, int nwg) {
  int qd = nwg >> 3, r = nwg & 7;
  int xcd = orig & 7, pos = orig >> 3;
  return (xcd < r ? xcd * (qd + 1) : r * (qd + 1) + (xcd - r) * qd) + pos;
}

// ---------------------------------------------------------------------------
// Transpose + split W [K][Ncols] fp32 -> Wt_h/Wt_l [Ncols][K] bf16.
// ---------------------------------------------------------------------------
__global__ __launch_bounds__(256) void wsplit_t(
    const float* __restrict__ W, int K, int Ncols,
    short* __restrict__ Wt_h, short* __restrict__ Wt_l) {
  __shared__ float t[32][33];
  const int n0 = blockIdx.x * 32, k0 = blockIdx.y * 32;
  const int tid = threadIdx.x;
  for (int e = tid; e < 1024; e += 256) {
    int r = e >> 5, c = e & 31;
    t[r][c] = W[(size_t)(k0 + r) * Ncols + n0 + c];
  }
  __syncthreads();
  for (int e = tid; e < 1024; e += 256) {
    int r = e >> 5, c = e & 31;  // r = n-local, c = k-local
    float f = t[c][r];
    short hi = f2bf(f);
    short lo = f2bf(f - bf2f(hi));
    size_t o = (size_t)(n0 + r) * K + k0 + c;
    Wt_h[o] = hi; Wt_l[o] = lo;
  }
}

// ---------------------------------------------------------------------------
// Elementwise split fp32 -> hi/lo bf16 (vectorized, grid-stride).
// ---------------------------------------------------------------------------
__global__ __launch_bounds__(256) void fsplit(
    const float* __restrict__ in, short* __restrict__ ho,
    short* __restrict__ lo_, int n4) {
  int stride = gridDim.x * 256;
  for (int i = blockIdx.x * 256 + threadIdx.x; i < n4; i += stride) {
    float4 f = ((const float4*)in)[i];
    short h0 = f2bf(f.x), h1 = f2bf(f.y), h2 = f2bf(f.z), h3 = f2bf(f.w);
    short l0 = f2bf(f.x - bf2f(h0)), l1 = f2bf(f.y - bf2f(h1));
    short l2 = f2bf(f.z - bf2f(h2)), l3 = f2bf(f.w - bf2f(h3));
    ((short4*)ho)[i] = make_short4(h0, h1, h2, h3);
    ((short4*)lo_)[i] = make_short4(l0, l1, l2, l3);
  }
}

// ---------------------------------------------------------------------------
// Pack int32 mask [B,H,N,M] -> bitmask [B,H,N,M/32] via wave ballot.
// ---------------------------------------------------------------------------
__global__ __launch_bounds__(256) void mask_pack(
    const int* __restrict__ mask, unsigned* __restrict__ pm) {
  const size_t total = (size_t)B_ * H_ * N_ * M_;
  const size_t stride = (size_t)gridDim.x * blockDim.x;
  const int lane = threadIdx.x & 63;
  for (size_t i = (size_t)blockIdx.x * blockDim.x + threadIdx.x; i < total;
       i += stride) {
    unsigned long long bal = __ballot(mask[i] != 0);
    if (lane == 0) *(unsigned long long*)(pm + (i >> 5)) = bal;
  }
}

// ---------------------------------------------------------------------------
// QKV GEMM (MFMA, split-bf16): A hi/lo bf16 [rows,768] @ Wt^T -> q/k hi/lo
// bf16 [B,H,rows,64] and v transposed bf16 [B,H,64,rows]. Tile 128x128.
// ---------------------------------------------------------------------------
__global__ __launch_bounds__(256) void qkv_mfma(
    const short* __restrict__ Ahp, const short* __restrict__ Alp,
    const short* __restrict__ Wth, const short* __restrict__ Wtl,
    int rowsPerB, int totalRows,
    short* __restrict__ qh, short* __restrict__ ql,
    short* __restrict__ kh, short* __restrict__ kl,
    short* __restrict__ vt) {
  __shared__ __align__(16) short As_h[128 * 40], As_l[128 * 40];
  __shared__ __align__(16) short Bs_h[128 * 40], Bs_l[128 * 40];
  const int nwg = gridDim.x * gridDim.y;
  const int nb = xcd_swizzle(blockIdx.y * gridDim.x + blockIdx.x, nwg);
  const int gx = gridDim.x;
  const int r0 = (nb / gx) * 128, c0 = (nb % gx) * 128;
  const int tid = threadIdx.x;
  const int w = tid >> 6, ln = tid & 63, q = ln >> 4, l15 = ln & 15;
  const int wM = (w & 1) * 64, wN = (w >> 1) * 64;
  const f32x4 z = {0.f, 0.f, 0.f, 0.f};
  f32x4 acc[4][4];
  for (int i = 0; i < 4; i++)
    for (int j = 0; j < 4; j++) acc[i][j] = z;
  for (int k0 = 0; k0 < DIM_; k0 += 32) {
    for (int e = tid; e < 512; e += 256) {
      int row = e >> 2, c = e & 3;
      int ar = r0 + row; if (ar >= totalRows) ar = totalRows - 1;
      size_t ga = (size_t)ar * DIM_ + k0 + c * 8;
      size_t gb = (size_t)(c0 + row) * DIM_ + k0 + c * 8;
      int o = row * 40 + c * 8;
      *(uint4*)(As_h + o) = *(const uint4*)(Ahp + ga);
      *(uint4*)(As_l + o) = *(const uint4*)(Alp + ga);
      *(uint4*)(Bs_h + o) = *(const uint4*)(Wth + gb);
      *(uint4*)(Bs_l + o) = *(const uint4*)(Wtl + gb);
    }
    __syncthreads();
    bf16x8 ah[4], al[4], bhf[4], blf[4];
    for (int mt = 0; mt < 4; mt++) {
      int o = (wM + mt * 16 + l15) * 40 + q * 8;
      ah[mt] = *(const bf16x8*)(As_h + o);
      al[mt] = *(const bf16x8*)(As_l + o);
    }
    for (int nt = 0; nt < 4; nt++) {
      int o = (wN + nt * 16 + l15) * 40 + q * 8;
      bhf[nt] = *(const bf16x8*)(Bs_h + o);
      blf[nt] = *(const bf16x8*)(Bs_l + o);
    }
    for (int mt = 0; mt < 4; mt++)
      for (int nt = 0; nt < 4; nt++) {
        f32x4 c = acc[mt][nt];
        c = MFMA16(ah[mt], bhf[nt], c);
        c = MFMA16(ah[mt], blf[nt], c);
        c = MFMA16(al[mt], bhf[nt], c);
        acc[mt][nt] = c;
      }
    __syncthreads();
  }
  for (int mt = 0; mt < 4; mt++)
    for (int nt = 0; nt < 4; nt++)
      for (int r = 0; r < 4; r++) {
        int gr = r0 + wM + mt * 16 + q * 4 + r;
        if (gr >= totalRows) continue;
        int gc = c0 + wN + nt * 16 + l15;
        int which = gc / DIM_;
        int rem = gc - which * DIM_;
        int hh = rem >> 6, d = rem & 63;
        int b = gr / rowsPerB, n = gr - b * rowsPerB;
        float v = acc[mt][nt][r];
        short hi = f2bf(v);
        if (which == 2) {
          vt[(((size_t)b * H_ + hh) * 64 + d) * rowsPerB + n] = hi;
        } else {
          short lo = f2bf(v - bf2f(hi));
          size_t o = (((size_t)b * H_ + hh) * rowsPerB + n) * 64 + d;
          if (which == 0) { qh[o] = hi; ql[o] = lo; }
          else           { kh[o] = hi; kl[o] = lo; }
        }
      }
}

// ---------------------------------------------------------------------------
// Output projection (MFMA, split-bf16): A hi/lo bf16 [rows,768] @ Wot^T + b.
// ---------------------------------------------------------------------------
__global__ __launch_bounds__(256) void proj_mfma(
    const short* __restrict__ Ahp, const short* __restrict__ Alp,
    const short* __restrict__ Bth, const short* __restrict__ Btl,
    const float* __restrict__ bias, float* __restrict__ C, int totalRows) {
  __shared__ __align__(16) short As_h[128 * 40], As_l[128 * 40];
  __shared__ __align__(16) short Bs_h[128 * 40], Bs_l[128 * 40];
  const int nwg = gridDim.x * gridDim.y;
  const int nb = xcd_swizzle(blockIdx.y * gridDim.x + blockIdx.x, nwg);
  const int gx = gridDim.x;
  const int r0 = (nb / gx) * 128, c0 = (nb % gx) * 128;
  const int tid = threadIdx.x;
  const int w = tid >> 6, ln = tid & 63, q = ln >> 4, l15 = ln & 15;
  const int wM = (w & 1) * 64, wN = (w >> 1) * 64;
  const f32x4 z = {0.f, 0.f, 0.f, 0.f};
  f32x4 acc[4][4];
  for (int i = 0; i < 4; i++)
    for (int j = 0; j < 4; j++) acc[i][j] = z;
  for (int k0 = 0; k0 < DIM_; k0 += 32) {
    for (int e = tid; e < 512; e += 256) {
      int row = e >> 2, c = e & 3;
      int ar = r0 + row; if (ar >= totalRows) ar = totalRows - 1;
      size_t ga = (size_t)ar * DIM_ + k0 + c * 8;
      size_t gb = (size_t)(c0 + row) * DIM_ + k0 + c * 8;
      int o = row * 40 + c * 8;
      *(uint4*)(As_h + o) = *(const uint4*)(Ahp + ga);
      *(uint4*)(As_l + o) = *(const uint4*)(Alp + ga);
      *(uint4*)(Bs_h + o) = *(const uint4*)(Bth + gb);
      *(uint4*)(Bs_l + o) = *(const uint4*)(Btl + gb);
    }
    __syncthreads();
    bf16x8 ah[4], al[4], bhf[4], blf[4];
    for (int mt = 0; mt < 4; mt++) {
      int o = (wM + mt * 16 + l15) * 40 + q * 8;
      ah[mt] = *(const bf16x8*)(As_h + o);
      al[mt] = *(const bf16x8*)(As_l + o);
    }
    for (int nt = 0; nt < 4; nt++) {
      int o = (wN + nt * 16 + l15) * 40 + q * 8;
      bhf[nt] = *(const bf16x8*)(Bs_h + o);
      blf[nt] = *(const bf16x8*)(Bs_l + o);
    }
    for (int mt = 0; mt < 4; mt++)
      for (int nt = 0; nt < 4; nt++) {
        f32x4 c = acc[mt][nt];
        c = MFMA16(ah[mt], bhf[nt], c);
        c = MFMA16(ah[mt], blf[nt], c);
        c = MFMA16(al[mt], bhf[nt], c);
        acc[mt][nt] = c;
      }
    __syncthreads();
  }
  for (int mt = 0; mt < 4; mt++)
    for (int nt = 0; nt < 4; nt++)
      for (int r = 0; r < 4; r++) {
        int gr = r0 + wM + mt * 16 + q * 4 + r;
        if (gr >= totalRows) continue;
        int gc = c0 + wN + nt * 16 + l15;
        C[(size_t)gr * DIM_ + gc] = acc[mt][nt][r] + bias[gc];
      }
}

// ---------------------------------------------------------------------------
// Branch 1 (MFMA): per (b,h,32 n-rows), 512 threads / 8 waves.
// QK^T split-bf16, two softmaxes over M=512, out3 write, P(hi/lo) @ V.
// Scores in LDS (col-XOR-swizzled); P overlays scores via register staging.
// krd prefetched into registers across the stats phase.
// ---------------------------------------------------------------------------
__global__ __launch_bounds__(512, 4) void branch1_mfma(
    const short* __restrict__ tqh, const short* __restrict__ tql,
    const short* __restrict__ kkh, const short* __restrict__ kkl,
    const short* __restrict__ kvt, const float* __restrict__ krd,
    const unsigned* __restrict__ pm, float* __restrict__ out3,
    short* __restrict__ amh, short* __restrict__ aml) {
  __shared__ __align__(16) float sc[32 * 520];  // 66560 B, aliased by P2h/P2l
  __shared__ unsigned mskw[512];                // 32 rows x 16 words
  __shared__ float rowM[32], inv1[32], inv2[32];
  short* P2h = (short*)sc;          // [32][520]
  short* P2l = P2h + 32 * 520;
  const int b = blockIdx.z, h = blockIdx.y, n0 = blockIdx.x * 32;
  const size_t bhi = (size_t)b * H_ + h;
  const int tid = threadIdx.x;
  const int w = tid >> 6, ln = tid & 63, q = ln >> 4, l15 = ln & 15;
  const float* krd0 = krd + bhi * M_ * N_;
  mskw[tid] = pm[(bhi * N_ + n0) * 16 + tid];
  // ---- QK^T: 32n x 512m, wave w -> ct in [4w, 4w+4) ----
  {
    bf16x8 ah[2][2], al[2][2];
    for (int mt = 0; mt < 2; mt++) {
      const short* ap = tqh + ((bhi * N_ + n0 + mt * 16 + l15) * D_ + q * 8);
      const short* ap2 = tql + ((bhi * N_ + n0 + mt * 16 + l15) * D_ + q * 8);
      ah[mt][0] = *(const bf16x8*)(ap);
      ah[mt][1] = *(const bf16x8*)(ap + 32);
      al[mt][0] = *(const bf16x8*)(ap2);
      al[mt][1] = *(const bf16x8*)(ap2 + 32);
    }
    for (int t = 0; t < 4; t++) {
      int ct = w * 4 + t;
      const short* bp = kkh + ((bhi * M_ + ct * 16 + l15) * D_ + q * 8);
      const short* bp2 = kkl + ((bhi * M_ + ct * 16 + l15) * D_ + q * 8);
      bf16x8 bh0 = *(const bf16x8*)(bp);
      bf16x8 bh1 = *(const bf16x8*)(bp + 32);
      bf16x8 bl0 = *(const bf16x8*)(bp2);
      bf16x8 bl1 = *(const bf16x8*)(bp2 + 32);
      for (int mt = 0; mt < 2; mt++) {
        f32x4 a = {0.f, 0.f, 0.f, 0.f};
        a = MFMA16(ah[mt][0], bh0, a); a = MFMA16(ah[mt][1], bh1, a);
        a = MFMA16(ah[mt][0], bl0, a); a = MFMA16(ah[mt][1], bl1, a);
        a = MFMA16(al[mt][0], bh0, a); a = MFMA16(al[mt][1], bh1, a);
        for (int r = 0; r < 4; r++) {
          int row = mt * 16 + q * 4 + r;
          sc[row * 520 + ((ct * 16 + l15) ^ ((row >> 2) & 7))] = a[r];
        }
      }
    }
  }
  // ---- prefetch krd for P-build (latency hides under stats phase) ----
  const int pi = tid & 31, pg = tid >> 5;
  float kr[32];
#pragma unroll
  for (int t = 0; t < 32; t++)
    kr[t] = krd0[(size_t)(pg * 32 + t) * N_ + n0 + pi];
  __syncthreads();
  // ---- mask + scale + row stats (both denominators) ----
  {
    int i = tid >> 4, jl = tid & 15;
    int sw = (i >> 2) & 7;
    float* scr = sc + i * 520;
    const unsigned* mrow = mskw + i * 16;
    float mx = -INFINITY;
    for (int j = jl; j < M_; j += 16) {
      float dv = scr[j ^ sw];
      dv = ((mrow[j >> 5] >> (j & 31)) & 1) ? NEG_ : dv * SCALE_;
      scr[j ^ sw] = dv;
      mx = fmaxf(mx, dv);
    }
    for (int o = 8; o >= 1; o >>= 1) mx = fmaxf(mx, __shfl_xor(mx, o, 16));
    float s1 = 0.f, s2 = 0.f;
    for (int j = jl; j < M_; j += 16) {
      float dv = scr[j ^ sw] - mx;
      s1 += __expf(dv * TEMP_);
      s2 += __expf(dv);
    }
    for (int o = 8; o >= 1; o >>= 1) {
      s1 += __shfl_xor(s1, o, 16);
      s2 += __shfl_xor(s2, o, 16);
    }
    if (jl == 0) { rowM[i] = mx; inv1[i] = 1.f / s1; inv2[i] = 1.f / s2; }
  }
  __syncthreads();
  // ---- P build: out3 write + P2 hi/lo (overlay sc via register staging) ----
  {
    float rv[32];
    int sw2 = (pi >> 2) & 7;
#pragma unroll
    for (int t = 0; t < 32; t++)
      rv[t] = sc[pi * 520 + ((pg * 32 + t) ^ sw2)];
    __syncthreads();
    float mx = rowM[pi], v1 = inv1[pi], v2 = inv2[pi];
    float* o3 = out3 + bhi * M_ * N_ + n0 + pi;
#pragma unroll 4
    for (int t = 0; t < 32; t += 2) {
      int j = pg * 32 + t;
      float dv0 = rv[t] - mx, dv1 = rv[t + 1] - mx;
      o3[(size_t)j * N_] = __expf(dv0 * TEMP_) * v1 * kr[t];
      o3[(size_t)(j + 1) * N_] = __expf(dv1 * TEMP_) * v1 * kr[t + 1];
      float p0 = __expf(dv0) * v2 * kr[t];
      float p1 = __expf(dv1) * v2 * kr[t + 1];
      short h0 = f2bf(p0), h1 = f2bf(p1);
      short lo0 = f2bf(p0 - bf2f(h0)), lo1 = f2bf(p1 - bf2f(h1));
      *(short2*)(P2h + pi * 520 + j) = make_short2(h0, h1);
      *(short2*)(P2l + pi * 520 + j) = make_short2(lo0, lo1);
    }
  }
  __syncthreads();
  // ---- PV: wave w -> (n-half, d-chunk) ----
  {
    const int dc = w & 3, nh = w >> 2;
    f32x4 o0 = {0.f, 0.f, 0.f, 0.f}, o1 = {0.f, 0.f, 0.f, 0.f};
    const short* vbase = kvt + ((bhi * 64 + dc * 16 + l15) * (size_t)M_ + q * 8);
    const short* ph = P2h + (nh * 16 + l15) * 520 + q * 8;
    const short* pl = P2l + (nh * 16 + l15) * 520 + q * 8;
    for (int kc = 0; kc < 16; kc += 2) {
      bf16x8 pa0 = *(const bf16x8*)(ph + kc * 32);
      bf16x8 pl0 = *(const bf16x8*)(pl + kc * 32);
      bf16x8 bv0 = *(const bf16x8*)(vbase + kc * 32);
      o0 = MFMA16(pa0, bv0, o0);
      o0 = MFMA16(pl0, bv0, o0);
      bf16x8 pa1 = *(const bf16x8*)(ph + (kc + 1) * 32);
      bf16x8 pl1 = *(const bf16x8*)(pl + (kc + 1) * 32);
      bf16x8 bv1 = *(const bf16x8*)(vbase + (kc + 1) * 32);
      o1 = MFMA16(pa1, bv1, o1);
      o1 = MFMA16(pl1, bv1, o1);
    }
    o0 += o1;
    for (int r = 0; r < 4; r++) {
      float v = o0[r];
      short hi = f2bf(v), lo = f2bf(v - bf2f(hi));
      size_t o = ((size_t)b * N_ + n0 + nh * 16 + q * 4 + r) * DIM_ +
                 h * 64 + dc * 16 + l15;
      amh[o] = hi; aml[o] = lo;
    }
  }
}

// ---------------------------------------------------------------------------
// Branch 2 (MFMA, flash): per (b,h,32 m-rows), loop n-chunks of 128.
// Mask comes from the packed bitmask: one word per n row.
// ---------------------------------------------------------------------------
__global__ __launch_bounds__(256) void branch2_mfma(
    const short* __restrict__ kqh, const short* __restrict__ kql,
    const short* __restrict__ tkh, const short* __restrict__ tkl,
    const short* __restrict__ tvt, const float* __restrict__ krd,
    const unsigned* __restrict__ pm, short* __restrict__ kmh,
    short* __restrict__ kml) {
  __shared__ __align__(16) float sc[32 * 136];  // 17408 B, aliased by P2h/P2l
  __shared__ unsigned mskw[128];
  __shared__ float rowM[32], rowL[32], alph[32];
  short* P2h = (short*)sc;          // [32][136]
  short* P2l = P2h + 32 * 136;
  const int b = blockIdx.z, h = blockIdx.y, m0 = blockIdx.x * 32;
  const size_t bhi = (size_t)b * H_ + h;
  const int tid = threadIdx.x;
  const int w = tid >> 6, ln = tid & 63, q = ln >> 4, l15 = ln & 15;
  const float* krd0 = krd + (bhi * M_ + m0) * N_;
  const int mword = m0 >> 5;
  bf16x8 Ah[2][2], Al[2][2];
  for (int mt = 0; mt < 2; mt++)
    for (int kc = 0; kc < 2; kc++) {
      size_t o = (bhi * M_ + m0 + mt * 16 + l15) * D_ + kc * 32 + q * 8;
      Ah[mt][kc] = *(const bf16x8*)(kqh + o);
      Al[mt][kc] = *(const bf16x8*)(kql + o);
    }
  if (tid < 32) { rowM[tid] = -INFINITY; rowL[tid] = 0.f; }
  const f32x4 z = {0.f, 0.f, 0.f, 0.f};
  f32x4 oa[2]; oa[0] = z; oa[1] = z;
  __syncthreads();
  for (int n0 = 0; n0 < N_; n0 += 128) {
    if (tid < 128) mskw[tid] = pm[(bhi * N_ + n0 + tid) * 16 + mword];
    for (int t = 0; t < 2; t++) {  // QK: wave w -> ct = 2w+t
      int ct = w * 2 + t;
      const short* bp = tkh + ((bhi * N_ + n0 + ct * 16 + l15) * D_ + q * 8);
      const short* bp2 = tkl + ((bhi * N_ + n0 + ct * 16 + l15) * D_ + q * 8);
      bf16x8 bh0 = *(const bf16x8*)(bp), bh1 = *(const bf16x8*)(bp + 32);
      bf16x8 bl0 = *(const bf16x8*)(bp2), bl1 = *(const bf16x8*)(bp2 + 32);
      for (int mt = 0; mt < 2; mt++) {
        f32x4 a = {0.f, 0.f, 0.f, 0.f};
        a = MFMA16(Ah[mt][0], bh0, a); a = MFMA16(Ah[mt][1], bh1, a);
        a = MFMA16(Ah[mt][0], bl0, a); a = MFMA16(Ah[mt][1], bl1, a);
        a = MFMA16(Al[mt][0], bh0, a); a = MFMA16(Al[mt][1], bh1, a);
        for (int r = 0; r < 4; r++)
          sc[(mt * 16 + q * 4 + r) * 136 + ct * 16 + l15] = a[r];
      }
    }
    __syncthreads();
    {  // online softmax: 8 threads/row
      int i = tid >> 3, jl = tid & 7;
      float mx = -INFINITY;
      for (int j = jl; j < 128; j += 8) {
        float s = sc[i * 136 + j];
        s = ((mskw[j] >> i) & 1) ? NEG_ : s * SCALE_;
        sc[i * 136 + j] = s;
        mx = fmaxf(mx, s);
      }
      for (int o = 4; o >= 1; o >>= 1) mx = fmaxf(mx, __shfl_xor(mx, o, 8));
      float mold = rowM[i];
      float mnew = fmaxf(mold, mx);
      float sum = 0.f;
      for (int j = jl; j < 128; j += 8) {
        float p = __expf(sc[i * 136 + j] - mnew);
        sc[i * 136 + j] = p;
        sum += p;
      }
      for (int o = 4; o >= 1; o >>= 1) sum += __shfl_xor(sum, o, 8);
      if (jl == 0) {
        float al = (mold == -INFINITY) ? 0.f : __expf(mold - mnew);
        alph[i] = al;
        rowL[i] = rowL[i] * al + sum;
        rowM[i] = mnew;
      }
    }
    __syncthreads();
    {  // P2 = p * krd, hi/lo (overlay sc via register staging)
      float rv[16];
      const int j = tid & 127;
      for (int t = 0; t < 16; t++) rv[t] = sc[((tid >> 7) + 2 * t) * 136 + j];
      __syncthreads();
      for (int t = 0; t < 16; t++) {
        int i = (tid >> 7) + 2 * t;
        float p2 = rv[t] * krd0[(size_t)i * N_ + n0 + j];
        short hi = f2bf(p2), lo = f2bf(p2 - bf2f(hi));
        P2h[i * 136 + j] = hi;
        P2l[i * 136 + j] = lo;
      }
    }
    __syncthreads();
    {  // PV accumulate, wave w -> dc = w
      for (int mt = 0; mt < 2; mt++) {
        f32x4 t = oa[mt];
        for (int r = 0; r < 4; r++) t[r] *= alph[mt * 16 + q * 4 + r];
        for (int kc = 0; kc < 4; kc++) {
          bf16x8 pa = *(const bf16x8*)(P2h + (mt * 16 + l15) * 136 + kc * 32 + q * 8);
          bf16x8 pl = *(const bf16x8*)(P2l + (mt * 16 + l15) * 136 + kc * 32 + q * 8);
          bf16x8 bv = *(const bf16x8*)(tvt + ((bhi * 64 + w * 16 + l15) * (size_t)N_ + n0 + kc * 32 + q * 8));
          t = MFMA16(pa, bv, t);
          t = MFMA16(pl, bv, t);
        }
        oa[mt] = t;
      }
    }
    __syncthreads();
  }
  for (int mt = 0; mt < 2; mt++)
    for (int r = 0; r < 4; r++) {
      int row = mt * 16 + q * 4 + r;
      float v = oa[mt][r] / rowL[row];
      short hi = f2bf(v), lo = f2bf(v - bf2f(hi));
      size_t o = ((size_t)b * M_ + m0 + row) * DIM_ + h * 64 + w * 16 + l15;
      kmh[o] = hi; kml[o] = lo;
    }
}

// ---------------------------------------------------------------------------
// Branch 3: cluster query per (b,h), vector math from hi/lo inputs.
// ---------------------------------------------------------------------------
__global__ __launch_bounds__(256) void branch3_k(
    const short* __restrict__ cqh, const short* __restrict__ cql,
    const short* __restrict__ kkh, const short* __restrict__ kkl,
    const short* __restrict__ kvt, const int* __restrict__ mask,
    short* __restrict__ cmh, short* __restrict__ cml) {
  const int h = blockIdx.x, b = blockIdx.y;
  __shared__ float qv[64];
  __shared__ float p[512];
  __shared__ float wr1[4], wr2[4];
  __shared__ float ored[4][64];
  const size_t bhi = (size_t)b * H_ + h;
  const int tid = threadIdx.x;
  if (tid < 64) qv[tid] = bf2f(cqh[bhi * 64 + tid]) + bf2f(cql[bhi * 64 + tid]);
  __syncthreads();
  const int* mask0 = mask + bhi * N_ * M_;  // row n = 0
  for (int j = tid; j < 512; j += 256) {
    float acc = 0;
    for (int kk = 0; kk < 64; kk++)
      acc += qv[kk] * (bf2f(kkh[(bhi * M_ + j) * 64 + kk]) +
                       bf2f(kkl[(bhi * M_ + j) * 64 + kk]));
    acc *= SCALE_;
    if (mask0[j]) acc = NEG_;
    p[j] = acc;
  }
  __syncthreads();
  float mx = fmaxf(p[tid], p[tid + 256]);
  for (int o = 32; o >= 1; o >>= 1) mx = fmaxf(mx, __shfl_xor(mx, o, 64));
  if ((tid & 63) == 0) wr1[tid >> 6] = mx;
  __syncthreads();
  mx = fmaxf(fmaxf(wr1[0], wr1[1]), fmaxf(wr1[2], wr1[3]));
  float e0 = __expf(p[tid] - mx), e1 = __expf(p[tid + 256] - mx);
  float s = e0 + e1;
  for (int o = 32; o >= 1; o >>= 1) s += __shfl_xor(s, o, 64);
  p[tid] = e0; p[tid + 256] = e1;
  if ((tid & 63) == 0) wr2[tid >> 6] = s;
  __syncthreads();
  float invS = 1.f / (wr2[0] + wr2[1] + wr2[2] + wr2[3]);
  int dd = tid & 63, gg = tid >> 6;
  float o = 0;
  for (int j = gg; j < 512; j += 4)
    o += p[j] * bf2f(kvt[(bhi * 64 + dd) * (size_t)M_ + j]);
  ored[gg][dd] = o;
  __syncthreads();
  if (gg == 0) {
    float r = (ored[0][dd] + ored[1][dd] + ored[2][dd] + ored[3][dd]) * invS;
    short hi = f2bf(r), lo = f2bf(r - bf2f(hi));
    cmh[(size_t)b * DIM_ + h * 64 + dd] = hi;
    cml[(size_t)b * DIM_ + h * 64 + dd] = lo;
  }
}

// ---------------------------------------------------------------------------
extern "C" void kernel_launch(void* const* d_in, const int* in_sizes, int n_in,
                              void* d_out, int out_size, void* d_ws,
                              size_t ws_size, hipStream_t stream) {
  const float* x = (const float*)d_in[0];
  const float* kx = (const float*)d_in[1];
  const float* krd = (const float*)d_in[2];
  const float* clst = (const float*)d_in[3];
  const int* mask = (const int*)d_in[4];
  const float* Wqkv = (const float*)d_in[5];
  const float* Wout = (const float*)d_in[6];
  const float* bout = (const float*)d_in[7];

  short* p = (short*)d_ws;
  auto alloc = [&](size_t n) { short* r = p; p += n; return r; };
  short* Wq_h = alloc(2304ull * 768); short* Wq_l = alloc(2304ull * 768);
  short* Wo_h = alloc(768ull * 768);  short* Wo_l = alloc(768ull * 768);
  short* tq_h = alloc(6291456); short* tq_l = alloc(6291456);
  short* tk_h = alloc(6291456); short* tk_l = alloc(6291456);
  short* tv_t = alloc(6291456);
  short* kq_h = alloc(1572864); short* kq_l = alloc(1572864);
  short* kk_h = alloc(1572864); short* kk_l = alloc(1572864);
  short* kv_t = alloc(1572864);
  short* cq_h = alloc(3072); short* cq_l = alloc(3072);
  short* ck_h = alloc(3072); short* ck_l = alloc(3072);
  short* cv_t = alloc(3072);
  short* am_h = alloc(6291456); short* am_l = alloc(6291456);
  short* km_h = alloc(1572864); short* km_l = alloc(1572864);
  short* cm_h = alloc(3072); short* cm_l = alloc(3072);

  float* out0 = (float*)d_out;        // [B,N,768]
  float* out1 = out0 + 6291456;       // [B,M,768]
  float* out2 = out1 + 1572864;       // [B,1,768]
  float* out3 = out2 + 3072;          // [B,H,M,N]

  wsplit_t<<<dim3(72, 24), 256, 0, stream>>>(Wqkv, DIM_, QKV_, Wq_h, Wq_l);
  wsplit_t<<<dim3(24, 24), 256, 0, stream>>>(Wout, DIM_, DIM_, Wo_h, Wo_l);

  // Pre-split activations fp32 -> hi/lo bf16. The split buffers alias the
  // am/km/cm workspace, which is dead until the branch kernels run.
  short* xs_h = am_h, *xs_l = am_l;     // [B*N,768]
  short* kxs_h = km_h, *kxs_l = km_l;   // [B*M,768]
  short* cs_h = cm_h, *cs_l = cm_l;     // [B,768]
  fsplit<<<dim3(2048), 256, 0, stream>>>(x, xs_h, xs_l, B_ * N_ * DIM_ / 4);
  fsplit<<<dim3(1536), 256, 0, stream>>>(kx, kxs_h, kxs_l, B_ * M_ * DIM_ / 4);
  fsplit<<<dim3(3), 256, 0, stream>>>(clst, cs_h, cs_l, B_ * DIM_ / 4);

  qkv_mfma<<<dim3(18, 64), 256, 0, stream>>>(xs_h, xs_l, Wq_h, Wq_l, N_,
                                             B_ * N_, tq_h, tq_l, tk_h, tk_l,
                                             tv_t);
  qkv_mfma<<<dim3(18, 16), 256, 0, stream>>>(kxs_h, kxs_l, Wq_h, Wq_l, M_,
                                             B_ * M_, kq_h, kq_l, kk_h, kk_l,
                                             kv_t);
  qkv_mfma<<<dim3(18, 1), 256, 0, stream>>>(cs_h, cs_l, Wq_h, Wq_l, 1, B_,
                                            cq_h, cq_l, ck_h, ck_l, cv_t);

  // Wq_h/Wq_l are dead after the qkv GEMMs; reuse their space for the packed
  // mask (needs 6.29 MB < 7.08 MB). Stream-ordered, so this is safe.
  unsigned* pmask = (unsigned*)Wq_h;
  mask_pack<<<dim3(2048), 256, 0, stream>>>(mask, pmask);

  branch1_mfma<<<dim3(N_ / 32, H_, B_), 512, 0, stream>>>(
      tq_h, tq_l, kk_h, kk_l, kv_t, krd, pmask, out3, am_h, am_l);
  branch2_mfma<<<dim3(M_ / 32, H_, B_), 256, 0, stream>>>(
      kq_h, kq_l, tk_h, tk_l, tv_t, krd, pmask, km_h, km_l);
  branch3_k<<<dim3(H_, B_), 256, 0, stream>>>(cq_h, cq_l, kk_h, kk_l, kv_t,
                                              mask, cm_h, cm_l);

  proj_mfma<<<dim3(6, 64), 256, 0, stream>>>(am_h, am_l, Wo_h, Wo_l, bout,
                                             out0, B_ * N_);
  proj_mfma<<<dim3(6, 16), 256, 0, stream>>>(km_h, km_l, Wo_h, Wo_l, bout,
                                             out1, B_ * M_);
  proj_mfma<<<dim3(6, 1), 256, 0, stream>>>(cm_h, cm_l, Wo_h, Wo_l, bout,
                                            out2, B_);
}

// Round 3
// 1207.142 us; speedup vs baseline: 1.2911x; 1.0220x over previous
//
#include <hip/hip_runtime.h>
#include <hip/hip_bf16.h>
#include <cmath>
#include <cstdint>

#define B_ 4
#define N_ 2048
#define M_ 512
#define H_ 12
#define D_ 64
#define DIM_ 768
#define QKV_ 2304
#define SCALE_ 0.125f
#define NEG_ -1e9f
#define TEMP_ 24.0f

typedef __attribute__((ext_vector_type(8))) short bf16x8;
typedef __attribute__((ext_vector_type(4))) float f32x4;

__device__ __forceinline__ short f2bf(float f) {
  union { float f; unsigned u; } v; v.f = f;
  unsigned r = v.u + 0x7fffu + ((v.u >> 16) & 1u);
  return (short)(r >> 16);
}
__device__ __forceinline__ float bf2f(short s) {
  union { unsigned u; float f; } v; v.u = ((unsigned)(unsigned short)s) << 16;
  return v.f;
}
#define MFMA16(a, b, c) __builtin_amdgcn_mfma_f32_16x16x32_bf16(a, b, c, 0, 0, 0)

// Bijective XCD-chunked swizzle (m204): consecutive remapped ids stay on one
// XCD so tiles sharing an A row-panel hit the same L2.
__device__ __forceinline__ int xcd_swizzle(int orig, int nwg) {
  int qd = nwg >> 3, r = nwg & 7;
  int xcd = orig & 7, pos = orig >> 3;
  return (xcd < r ? xcd * (qd + 1) : r * (qd + 1) + (xcd - r) * qd) + pos;
}

// ---------------------------------------------------------------------------
// Transpose + split W [K][Ncols] fp32 -> Wt_h/Wt_l [Ncols][K] bf16.
// ---------------------------------------------------------------------------
__global__ __launch_bounds__(256) void wsplit_t(
    const float* __restrict__ W, int K, int Ncols,
    short* __restrict__ Wt_h, short* __restrict__ Wt_l) {
  __shared__ float t[32][33];
  const int n0 = blockIdx.x * 32, k0 = blockIdx.y * 32;
  const int tid = threadIdx.x;
  for (int e = tid; e < 1024; e += 256) {
    int r = e >> 5, c = e & 31;
    t[r][c] = W[(size_t)(k0 + r) * Ncols + n0 + c];
  }
  __syncthreads();
  for (int e = tid; e < 1024; e += 256) {
    int r = e >> 5, c = e & 31;  // r = n-local, c = k-local
    float f = t[c][r];
    short hi = f2bf(f);
    short lo = f2bf(f - bf2f(hi));
    size_t o = (size_t)(n0 + r) * K + k0 + c;
    Wt_h[o] = hi; Wt_l[o] = lo;
  }
}

// ---------------------------------------------------------------------------
// Elementwise split fp32 -> hi/lo bf16 (vectorized, grid-stride).
// ---------------------------------------------------------------------------
__global__ __launch_bounds__(256) void fsplit(
    const float* __restrict__ in, short* __restrict__ ho,
    short* __restrict__ lo_, int n4) {
  int stride = gridDim.x * 256;
  for (int i = blockIdx.x * 256 + threadIdx.x; i < n4; i += stride) {
    float4 f = ((const float4*)in)[i];
    short h0 = f2bf(f.x), h1 = f2bf(f.y), h2 = f2bf(f.z), h3 = f2bf(f.w);
    short l0 = f2bf(f.x - bf2f(h0)), l1 = f2bf(f.y - bf2f(h1));
    short l2 = f2bf(f.z - bf2f(h2)), l3 = f2bf(f.w - bf2f(h3));
    ((short4*)ho)[i] = make_short4(h0, h1, h2, h3);
    ((short4*)lo_)[i] = make_short4(l0, l1, l2, l3);
  }
}

// ---------------------------------------------------------------------------
// Pack int32 mask [B,H,N,M] -> bitmask [B,H,N,M/32] via wave ballot.
// ---------------------------------------------------------------------------
__global__ __launch_bounds__(256) void mask_pack(
    const int* __restrict__ mask, unsigned* __restrict__ pm) {
  const size_t total = (size_t)B_ * H_ * N_ * M_;
  const size_t stride = (size_t)gridDim.x * blockDim.x;
  const int lane = threadIdx.x & 63;
  for (size_t i = (size_t)blockIdx.x * blockDim.x + threadIdx.x; i < total;
       i += stride) {
    unsigned long long bal = __ballot(mask[i] != 0);
    if (lane == 0) *(unsigned long long*)(pm + (i >> 5)) = bal;
  }
}

// ---------------------------------------------------------------------------
// QKV GEMM (MFMA, split-bf16): A hi/lo bf16 [rows,768] @ Wt^T -> q/k hi/lo
// bf16 [B,H,rows,64] and v transposed bf16 [B,H,64,rows]. Tile 128x128.
// ---------------------------------------------------------------------------
__global__ __launch_bounds__(256) void qkv_mfma(
    const short* __restrict__ Ahp, const short* __restrict__ Alp,
    const short* __restrict__ Wth, const short* __restrict__ Wtl,
    int rowsPerB, int totalRows,
    short* __restrict__ qh, short* __restrict__ ql,
    short* __restrict__ kh, short* __restrict__ kl,
    short* __restrict__ vt) {
  __shared__ __align__(16) short As_h[128 * 40], As_l[128 * 40];
  __shared__ __align__(16) short Bs_h[128 * 40], Bs_l[128 * 40];
  const int nwg = gridDim.x * gridDim.y;
  const int nb = xcd_swizzle(blockIdx.y * gridDim.x + blockIdx.x, nwg);
  const int gx = gridDim.x;
  const int r0 = (nb / gx) * 128, c0 = (nb % gx) * 128;
  const int tid = threadIdx.x;
  const int w = tid >> 6, ln = tid & 63, q = ln >> 4, l15 = ln & 15;
  const int wM = (w & 1) * 64, wN = (w >> 1) * 64;
  const f32x4 z = {0.f, 0.f, 0.f, 0.f};
  f32x4 acc[4][4];
  for (int i = 0; i < 4; i++)
    for (int j = 0; j < 4; j++) acc[i][j] = z;
  for (int k0 = 0; k0 < DIM_; k0 += 32) {
    for (int e = tid; e < 512; e += 256) {
      int row = e >> 2, c = e & 3;
      int ar = r0 + row; if (ar >= totalRows) ar = totalRows - 1;
      size_t ga = (size_t)ar * DIM_ + k0 + c * 8;
      size_t gb = (size_t)(c0 + row) * DIM_ + k0 + c * 8;
      int o = row * 40 + c * 8;
      *(uint4*)(As_h + o) = *(const uint4*)(Ahp + ga);
      *(uint4*)(As_l + o) = *(const uint4*)(Alp + ga);
      *(uint4*)(Bs_h + o) = *(const uint4*)(Wth + gb);
      *(uint4*)(Bs_l + o) = *(const uint4*)(Wtl + gb);
    }
    __syncthreads();
    bf16x8 ah[4], al[4], bhf[4], blf[4];
    for (int mt = 0; mt < 4; mt++) {
      int o = (wM + mt * 16 + l15) * 40 + q * 8;
      ah[mt] = *(const bf16x8*)(As_h + o);
      al[mt] = *(const bf16x8*)(As_l + o);
    }
    for (int nt = 0; nt < 4; nt++) {
      int o = (wN + nt * 16 + l15) * 40 + q * 8;
      bhf[nt] = *(const bf16x8*)(Bs_h + o);
      blf[nt] = *(const bf16x8*)(Bs_l + o);
    }
    for (int mt = 0; mt < 4; mt++)
      for (int nt = 0; nt < 4; nt++) {
        f32x4 c = acc[mt][nt];
        c = MFMA16(ah[mt], bhf[nt], c);
        c = MFMA16(ah[mt], blf[nt], c);
        c = MFMA16(al[mt], bhf[nt], c);
        acc[mt][nt] = c;
      }
    __syncthreads();
  }
  for (int mt = 0; mt < 4; mt++)
    for (int nt = 0; nt < 4; nt++)
      for (int r = 0; r < 4; r++) {
        int gr = r0 + wM + mt * 16 + q * 4 + r;
        if (gr >= totalRows) continue;
        int gc = c0 + wN + nt * 16 + l15;
        int which = gc / DIM_;
        int rem = gc - which * DIM_;
        int hh = rem >> 6, d = rem & 63;
        int b = gr / rowsPerB, n = gr - b * rowsPerB;
        float v = acc[mt][nt][r];
        short hi = f2bf(v);
        if (which == 2) {
          vt[(((size_t)b * H_ + hh) * 64 + d) * rowsPerB + n] = hi;
        } else {
          short lo = f2bf(v - bf2f(hi));
          size_t o = (((size_t)b * H_ + hh) * rowsPerB + n) * 64 + d;
          if (which == 0) { qh[o] = hi; ql[o] = lo; }
          else           { kh[o] = hi; kl[o] = lo; }
        }
      }
}

// ---------------------------------------------------------------------------
// Output projection (MFMA, split-bf16): A hi/lo bf16 [rows,768] @ Wot^T + b.
// ---------------------------------------------------------------------------
__global__ __launch_bounds__(256) void proj_mfma(
    const short* __restrict__ Ahp, const short* __restrict__ Alp,
    const short* __restrict__ Bth, const short* __restrict__ Btl,
    const float* __restrict__ bias, float* __restrict__ C, int totalRows) {
  __shared__ __align__(16) short As_h[128 * 40], As_l[128 * 40];
  __shared__ __align__(16) short Bs_h[128 * 40], Bs_l[128 * 40];
  const int nwg = gridDim.x * gridDim.y;
  const int nb = xcd_swizzle(blockIdx.y * gridDim.x + blockIdx.x, nwg);
  const int gx = gridDim.x;
  const int r0 = (nb / gx) * 128, c0 = (nb % gx) * 128;
  const int tid = threadIdx.x;
  const int w = tid >> 6, ln = tid & 63, q = ln >> 4, l15 = ln & 15;
  const int wM = (w & 1) * 64, wN = (w >> 1) * 64;
  const f32x4 z = {0.f, 0.f, 0.f, 0.f};
  f32x4 acc[4][4];
  for (int i = 0; i < 4; i++)
    for (int j = 0; j < 4; j++) acc[i][j] = z;
  for (int k0 = 0; k0 < DIM_; k0 += 32) {
    for (int e = tid; e < 512; e += 256) {
      int row = e >> 2, c = e & 3;
      int ar = r0 + row; if (ar >= totalRows) ar = totalRows - 1;
      size_t ga = (size_t)ar * DIM_ + k0 + c * 8;
      size_t gb = (size_t)(c0 + row) * DIM_ + k0 + c * 8;
      int o = row * 40 + c * 8;
      *(uint4*)(As_h + o) = *(const uint4*)(Ahp + ga);
      *(uint4*)(As_l + o) = *(const uint4*)(Alp + ga);
      *(uint4*)(Bs_h + o) = *(const uint4*)(Bth + gb);
      *(uint4*)(Bs_l + o) = *(const uint4*)(Btl + gb);
    }
    __syncthreads();
    bf16x8 ah[4], al[4], bhf[4], blf[4];
    for (int mt = 0; mt < 4; mt++) {
      int o = (wM + mt * 16 + l15) * 40 + q * 8;
      ah[mt] = *(const bf16x8*)(As_h + o);
      al[mt] = *(const bf16x8*)(As_l + o);
    }
    for (int nt = 0; nt < 4; nt++) {
      int o = (wN + nt * 16 + l15) * 40 + q * 8;
      bhf[nt] = *(const bf16x8*)(Bs_h + o);
      blf[nt] = *(const bf16x8*)(Bs_l + o);
    }
    for (int mt = 0; mt < 4; mt++)
      for (int nt = 0; nt < 4; nt++) {
        f32x4 c = acc[mt][nt];
        c = MFMA16(ah[mt], bhf[nt], c);
        c = MFMA16(ah[mt], blf[nt], c);
        c = MFMA16(al[mt], bhf[nt], c);
        acc[mt][nt] = c;
      }
    __syncthreads();
  }
  for (int mt = 0; mt < 4; mt++)
    for (int nt = 0; nt < 4; nt++)
      for (int r = 0; r < 4; r++) {
        int gr = r0 + wM + mt * 16 + q * 4 + r;
        if (gr >= totalRows) continue;
        int gc = c0 + wN + nt * 16 + l15;
        C[(size_t)gr * DIM_ + gc] = acc[mt][nt][r] + bias[gc];
      }
}

// ---------------------------------------------------------------------------
// Branch 1 (MFMA): per (b,h,32 n-rows), 512 threads / 8 waves.
// QK^T split-bf16, two softmaxes over M=512, out3 write, P(hi/lo) @ V.
// Scores in LDS (col-XOR-swizzled); P overlays scores via register staging.
// kr/rv arrays are FULLY unrolled (static indices) so they live in VGPRs,
// not scratch. exp() is computed once per element; the TEMP=24 softmax
// numerator is reconstructed as e2^24 (5 mults), consistent num/denom.
// ---------------------------------------------------------------------------
__global__ __launch_bounds__(512, 4) void branch1_mfma(
    const short* __restrict__ tqh, const short* __restrict__ tql,
    const short* __restrict__ kkh, const short* __restrict__ kkl,
    const short* __restrict__ kvt, const float* __restrict__ krd,
    const unsigned* __restrict__ pm, float* __restrict__ out3,
    short* __restrict__ amh, short* __restrict__ aml) {
  __shared__ __align__(16) float sc[32 * 520];  // 66560 B, aliased by P2h/P2l
  __shared__ unsigned mskw[512];                // 32 rows x 16 words
  __shared__ float rowM[32], inv1[32], inv2[32];
  short* P2h = (short*)sc;          // [32][520]
  short* P2l = P2h + 32 * 520;
  const int b = blockIdx.z, h = blockIdx.y, n0 = blockIdx.x * 32;
  const size_t bhi = (size_t)b * H_ + h;
  const int tid = threadIdx.x;
  const int w = tid >> 6, ln = tid & 63, q = ln >> 4, l15 = ln & 15;
  const float* krd0 = krd + bhi * M_ * N_;
  mskw[tid] = pm[(bhi * N_ + n0) * 16 + tid];
  // ---- QK^T: 32n x 512m, wave w -> ct in [4w, 4w+4) ----
  {
    bf16x8 ah[2][2], al[2][2];
    for (int mt = 0; mt < 2; mt++) {
      const short* ap = tqh + ((bhi * N_ + n0 + mt * 16 + l15) * D_ + q * 8);
      const short* ap2 = tql + ((bhi * N_ + n0 + mt * 16 + l15) * D_ + q * 8);
      ah[mt][0] = *(const bf16x8*)(ap);
      ah[mt][1] = *(const bf16x8*)(ap + 32);
      al[mt][0] = *(const bf16x8*)(ap2);
      al[mt][1] = *(const bf16x8*)(ap2 + 32);
    }
    for (int t = 0; t < 4; t++) {
      int ct = w * 4 + t;
      const short* bp = kkh + ((bhi * M_ + ct * 16 + l15) * D_ + q * 8);
      const short* bp2 = kkl + ((bhi * M_ + ct * 16 + l15) * D_ + q * 8);
      bf16x8 bh0 = *(const bf16x8*)(bp);
      bf16x8 bh1 = *(const bf16x8*)(bp + 32);
      bf16x8 bl0 = *(const bf16x8*)(bp2);
      bf16x8 bl1 = *(const bf16x8*)(bp2 + 32);
      for (int mt = 0; mt < 2; mt++) {
        f32x4 a = {0.f, 0.f, 0.f, 0.f};
        a = MFMA16(ah[mt][0], bh0, a); a = MFMA16(ah[mt][1], bh1, a);
        a = MFMA16(ah[mt][0], bl0, a); a = MFMA16(ah[mt][1], bl1, a);
        a = MFMA16(al[mt][0], bh0, a); a = MFMA16(al[mt][1], bh1, a);
        for (int r = 0; r < 4; r++) {
          int row = mt * 16 + q * 4 + r;
          sc[row * 520 + ((ct * 16 + l15) ^ ((row >> 2) & 7))] = a[r];
        }
      }
    }
  }
  // ---- prefetch krd for P-build (latency hides under stats phase) ----
  const int pi = tid & 31, pg = tid >> 5;
  float kr[32];
#pragma unroll
  for (int t = 0; t < 32; t++)
    kr[t] = __builtin_nontemporal_load(
        krd0 + (size_t)(pg * 32 + t) * N_ + n0 + pi);
  __syncthreads();
  // ---- mask + scale + row stats; sc ends holding e2 = exp(dv - mx) ----
  {
    int i = tid >> 4, jl = tid & 15;
    int sw = (i >> 2) & 7;
    float* scr = sc + i * 520;
    const unsigned* mrow = mskw + i * 16;
    float mx = -INFINITY;
    for (int j = jl; j < M_; j += 16) {
      float dv = scr[j ^ sw];
      dv = ((mrow[j >> 5] >> (j & 31)) & 1) ? NEG_ : dv * SCALE_;
      scr[j ^ sw] = dv;
      mx = fmaxf(mx, dv);
    }
    for (int o = 8; o >= 1; o >>= 1) mx = fmaxf(mx, __shfl_xor(mx, o, 16));
    float s1 = 0.f, s2 = 0.f;
    for (int j = jl; j < M_; j += 16) {
      float e2 = __expf(scr[j ^ sw] - mx);
      scr[j ^ sw] = e2;
      float x2 = e2 * e2, x4 = x2 * x2, x8 = x4 * x4, x16 = x8 * x8;
      s1 += x16 * x8;   // e2^24
      s2 += e2;
    }
    for (int o = 8; o >= 1; o >>= 1) {
      s1 += __shfl_xor(s1, o, 16);
      s2 += __shfl_xor(s2, o, 16);
    }
    if (jl == 0) { inv1[i] = 1.f / s1; inv2[i] = 1.f / s2; }
  }
  __syncthreads();
  // ---- P build: out3 write + P2 hi/lo (overlay sc via register staging) ----
  {
    float rv[32];
    int sw2 = (pi >> 2) & 7;
#pragma unroll
    for (int t = 0; t < 32; t++)
      rv[t] = sc[pi * 520 + ((pg * 32 + t) ^ sw2)];
    __syncthreads();
    float v1 = inv1[pi], v2 = inv2[pi];
    float* o3 = out3 + bhi * M_ * N_ + n0 + pi;
#pragma unroll
    for (int t = 0; t < 32; t += 2) {
      int j = pg * 32 + t;
      float e2a = rv[t], e2b = rv[t + 1];
      float a2 = e2a * e2a, a4 = a2 * a2, a8 = a4 * a4, a16 = a8 * a8;
      float b2 = e2b * e2b, b4 = b2 * b2, b8 = b4 * b4, b16 = b8 * b8;
      __builtin_nontemporal_store(a16 * a8 * v1 * kr[t], o3 + (size_t)j * N_);
      __builtin_nontemporal_store(b16 * b8 * v1 * kr[t + 1],
                                  o3 + (size_t)(j + 1) * N_);
      float p0 = e2a * v2 * kr[t];
      float p1 = e2b * v2 * kr[t + 1];
      short h0 = f2bf(p0), h1 = f2bf(p1);
      short lo0 = f2bf(p0 - bf2f(h0)), lo1 = f2bf(p1 - bf2f(h1));
      *(short2*)(P2h + pi * 520 + j) = make_short2(h0, h1);
      *(short2*)(P2l + pi * 520 + j) = make_short2(lo0, lo1);
    }
  }
  __syncthreads();
  // ---- PV: wave w -> (n-half, d-chunk) ----
  {
    const int dc = w & 3, nh = w >> 2;
    f32x4 o0 = {0.f, 0.f, 0.f, 0.f}, o1 = {0.f, 0.f, 0.f, 0.f};
    const short* vbase = kvt + ((bhi * 64 + dc * 16 + l15) * (size_t)M_ + q * 8);
    const short* ph = P2h + (nh * 16 + l15) * 520 + q * 8;
    const short* pl = P2l + (nh * 16 + l15) * 520 + q * 8;
    for (int kc = 0; kc < 16; kc += 2) {
      bf16x8 pa0 = *(const bf16x8*)(ph + kc * 32);
      bf16x8 pl0 = *(const bf16x8*)(pl + kc * 32);
      bf16x8 bv0 = *(const bf16x8*)(vbase + kc * 32);
      o0 = MFMA16(pa0, bv0, o0);
      o0 = MFMA16(pl0, bv0, o0);
      bf16x8 pa1 = *(const bf16x8*)(ph + (kc + 1) * 32);
      bf16x8 pl1 = *(const bf16x8*)(pl + (kc + 1) * 32);
      bf16x8 bv1 = *(const bf16x8*)(vbase + (kc + 1) * 32);
      o1 = MFMA16(pa1, bv1, o1);
      o1 = MFMA16(pl1, bv1, o1);
    }
    o0 += o1;
    for (int r = 0; r < 4; r++) {
      float v = o0[r];
      short hi = f2bf(v), lo = f2bf(v - bf2f(hi));
      size_t o = ((size_t)b * N_ + n0 + nh * 16 + q * 4 + r) * DIM_ +
                 h * 64 + dc * 16 + l15;
      amh[o] = hi; aml[o] = lo;
    }
  }
}

// ---------------------------------------------------------------------------
// Branch 2 (MFMA, flash): per (b,h,32 m-rows), loop n-chunks of 128.
// Mask comes from the packed bitmask: one word per n row.
// ---------------------------------------------------------------------------
__global__ __launch_bounds__(256) void branch2_mfma(
    const short* __restrict__ kqh, const short* __restrict__ kql,
    const short* __restrict__ tkh, const short* __restrict__ tkl,
    const short* __restrict__ tvt, const float* __restrict__ krd,
    const unsigned* __restrict__ pm, short* __restrict__ kmh,
    short* __restrict__ kml) {
  __shared__ __align__(16) float sc[32 * 136];  // 17408 B, aliased by P2h/P2l
  __shared__ unsigned mskw[128];
  __shared__ float rowM[32], rowL[32], alph[32];
  short* P2h = (short*)sc;          // [32][136]
  short* P2l = P2h + 32 * 136;
  const int b = blockIdx.z, h = blockIdx.y, m0 = blockIdx.x * 32;
  const size_t bhi = (size_t)b * H_ + h;
  const int tid = threadIdx.x;
  const int w = tid >> 6, ln = tid & 63, q = ln >> 4, l15 = ln & 15;
  const float* krd0 = krd + (bhi * M_ + m0) * N_;
  const int mword = m0 >> 5;
  bf16x8 Ah[2][2], Al[2][2];
  for (int mt = 0; mt < 2; mt++)
    for (int kc = 0; kc < 2; kc++) {
      size_t o = (bhi * M_ + m0 + mt * 16 + l15) * D_ + kc * 32 + q * 8;
      Ah[mt][kc] = *(const bf16x8*)(kqh + o);
      Al[mt][kc] = *(const bf16x8*)(kql + o);
    }
  if (tid < 32) { rowM[tid] = -INFINITY; rowL[tid] = 0.f; }
  const f32x4 z = {0.f, 0.f, 0.f, 0.f};
  f32x4 oa[2]; oa[0] = z; oa[1] = z;
  __syncthreads();
  for (int n0 = 0; n0 < N_; n0 += 128) {
    if (tid < 128) mskw[tid] = pm[(bhi * N_ + n0 + tid) * 16 + mword];
    for (int t = 0; t < 2; t++) {  // QK: wave w -> ct = 2w+t
      int ct = w * 2 + t;
      const short* bp = tkh + ((bhi * N_ + n0 + ct * 16 + l15) * D_ + q * 8);
      const short* bp2 = tkl + ((bhi * N_ + n0 + ct * 16 + l15) * D_ + q * 8);
      bf16x8 bh0 = *(const bf16x8*)(bp), bh1 = *(const bf16x8*)(bp + 32);
      bf16x8 bl0 = *(const bf16x8*)(bp2), bl1 = *(const bf16x8*)(bp2 + 32);
      for (int mt = 0; mt < 2; mt++) {
        f32x4 a = {0.f, 0.f, 0.f, 0.f};
        a = MFMA16(Ah[mt][0], bh0, a); a = MFMA16(Ah[mt][1], bh1, a);
        a = MFMA16(Ah[mt][0], bl0, a); a = MFMA16(Ah[mt][1], bl1, a);
        a = MFMA16(Al[mt][0], bh0, a); a = MFMA16(Al[mt][1], bh1, a);
        for (int r = 0; r < 4; r++)
          sc[(mt * 16 + q * 4 + r) * 136 + ct * 16 + l15] = a[r];
      }
    }
    __syncthreads();
    {  // online softmax: 8 threads/row
      int i = tid >> 3, jl = tid & 7;
      float mx = -INFINITY;
      for (int j = jl; j < 128; j += 8) {
        float s = sc[i * 136 + j];
        s = ((mskw[j] >> i) & 1) ? NEG_ : s * SCALE_;
        sc[i * 136 + j] = s;
        mx = fmaxf(mx, s);
      }
      for (int o = 4; o >= 1; o >>= 1) mx = fmaxf(mx, __shfl_xor(mx, o, 8));
      float mold = rowM[i];
      float mnew = fmaxf(mold, mx);
      float sum = 0.f;
      for (int j = jl; j < 128; j += 8) {
        float p = __expf(sc[i * 136 + j] - mnew);
        sc[i * 136 + j] = p;
        sum += p;
      }
      for (int o = 4; o >= 1; o >>= 1) sum += __shfl_xor(sum, o, 8);
      if (jl == 0) {
        float al = (mold == -INFINITY) ? 0.f : __expf(mold - mnew);
        alph[i] = al;
        rowL[i] = rowL[i] * al + sum;
        rowM[i] = mnew;
      }
    }
    __syncthreads();
    {  // P2 = p * krd, hi/lo (overlay sc via register staging)
      float rv[16], kv2[16];
      const int j = tid & 127;
      const int ib = tid >> 7;
#pragma unroll
      for (int t = 0; t < 16; t++) {
        rv[t] = sc[(ib + 2 * t) * 136 + j];
        kv2[t] = __builtin_nontemporal_load(
            krd0 + (size_t)(ib + 2 * t) * N_ + n0 + j);
      }
      __syncthreads();
#pragma unroll
      for (int t = 0; t < 16; t++) {
        int i = ib + 2 * t;
        float p2 = rv[t] * kv2[t];
        short hi = f2bf(p2), lo = f2bf(p2 - bf2f(hi));
        P2h[i * 136 + j] = hi;
        P2l[i * 136 + j] = lo;
      }
    }
    __syncthreads();
    {  // PV accumulate, wave w -> dc = w
      for (int mt = 0; mt < 2; mt++) {
        f32x4 t = oa[mt];
        for (int r = 0; r < 4; r++) t[r] *= alph[mt * 16 + q * 4 + r];
        for (int kc = 0; kc < 4; kc++) {
          bf16x8 pa = *(const bf16x8*)(P2h + (mt * 16 + l15) * 136 + kc * 32 + q * 8);
          bf16x8 pl = *(const bf16x8*)(P2l + (mt * 16 + l15) * 136 + kc * 32 + q * 8);
          bf16x8 bv = *(const bf16x8*)(tvt + ((bhi * 64 + w * 16 + l15) * (size_t)N_ + n0 + kc * 32 + q * 8));
          t = MFMA16(pa, bv, t);
          t = MFMA16(pl, bv, t);
        }
        oa[mt] = t;
      }
    }
    __syncthreads();
  }
  for (int mt = 0; mt < 2; mt++)
    for (int r = 0; r < 4; r++) {
      int row = mt * 16 + q * 4 + r;
      float v = oa[mt][r] / rowL[row];
      short hi = f2bf(v), lo = f2bf(v - bf2f(hi));
      size_t o = ((size_t)b * M_ + m0 + row) * DIM_ + h * 64 + w * 16 + l15;
      kmh[o] = hi; kml[o] = lo;
    }
}

// ---------------------------------------------------------------------------
// Branch 3: cluster query per (b,h), vector math from hi/lo inputs.
// ---------------------------------------------------------------------------
__global__ __launch_bounds__(256) void branch3_k(
    const short* __restrict__ cqh, const short* __restrict__ cql,
    const short* __restrict__ kkh, const short* __restrict__ kkl,
    const short* __restrict__ kvt, const unsigned* __restrict__ pm,
    short* __restrict__ cmh, short* __restrict__ cml) {
  const int h = blockIdx.x, b = blockIdx.y;
  __shared__ float qv[64];
  __shared__ float p[512];
  __shared__ float wr1[4], wr2[4];
  __shared__ float ored[4][64];
  const size_t bhi = (size_t)b * H_ + h;
  const int tid = threadIdx.x;
  if (tid < 64) qv[tid] = bf2f(cqh[bhi * 64 + tid]) + bf2f(cql[bhi * 64 + tid]);
  __syncthreads();
  const unsigned* m0p = pm + bhi * N_ * 16;  // row n = 0
  for (int j = tid; j < 512; j += 256) {
    float acc = 0;
    for (int kk = 0; kk < 64; kk++)
      acc += qv[kk] * (bf2f(kkh[(bhi * M_ + j) * 64 + kk]) +
                       bf2f(kkl[(bhi * M_ + j) * 64 + kk]));
    acc *= SCALE_;
    if ((m0p[j >> 5] >> (j & 31)) & 1) acc = NEG_;
    p[j] = acc;
  }
  __syncthreads();
  float mx = fmaxf(p[tid], p[tid + 256]);
  for (int o = 32; o >= 1; o >>= 1) mx = fmaxf(mx, __shfl_xor(mx, o, 64));
  if ((tid & 63) == 0) wr1[tid >> 6] = mx;
  __syncthreads();
  mx = fmaxf(fmaxf(wr1[0], wr1[1]), fmaxf(wr1[2], wr1[3]));
  float e0 = __expf(p[tid] - mx), e1 = __expf(p[tid + 256] - mx);
  float s = e0 + e1;
  for (int o = 32; o >= 1; o >>= 1) s += __shfl_xor(s, o, 64);
  p[tid] = e0; p[tid + 256] = e1;
  if ((tid & 63) == 0) wr2[tid >> 6] = s;
  __syncthreads();
  float invS = 1.f / (wr2[0] + wr2[1] + wr2[2] + wr2[3]);
  int dd = tid & 63, gg = tid >> 6;
  float o = 0;
  for (int j = gg; j < 512; j += 4)
    o += p[j] * bf2f(kvt[(bhi * 64 + dd) * (size_t)M_ + j]);
  ored[gg][dd] = o;
  __syncthreads();
  if (gg == 0) {
    float r = (ored[0][dd] + ored[1][dd] + ored[2][dd] + ored[3][dd]) * invS;
    short hi = f2bf(r), lo = f2bf(r - bf2f(hi));
    cmh[(size_t)b * DIM_ + h * 64 + dd] = hi;
    cml[(size_t)b * DIM_ + h * 64 + dd] = lo;
  }
}

// ---------------------------------------------------------------------------
extern "C" void kernel_launch(void* const* d_in, const int* in_sizes, int n_in,
                              void* d_out, int out_size, void* d_ws,
                              size_t ws_size, hipStream_t stream) {
  const float* x = (const float*)d_in[0];
  const float* kx = (const float*)d_in[1];
  const float* krd = (const float*)d_in[2];
  const float* clst = (const float*)d_in[3];
  const int* mask = (const int*)d_in[4];
  const float* Wqkv = (const float*)d_in[5];
  const float* Wout = (const float*)d_in[6];
  const float* bout = (const float*)d_in[7];

  short* p = (short*)d_ws;
  auto alloc = [&](size_t n) { short* r = p; p += n; return r; };
  short* Wq_h = alloc(2304ull * 768); short* Wq_l = alloc(2304ull * 768);
  short* Wo_h = alloc(768ull * 768);  short* Wo_l = alloc(768ull * 768);
  short* tq_h = alloc(6291456); short* tq_l = alloc(6291456);
  short* tk_h = alloc(6291456); short* tk_l = alloc(6291456);
  short* tv_t = alloc(6291456);
  short* kq_h = alloc(1572864); short* kq_l = alloc(1572864);
  short* kk_h = alloc(1572864); short* kk_l = alloc(1572864);
  short* kv_t = alloc(1572864);
  short* cq_h = alloc(3072); short* cq_l = alloc(3072);
  short* ck_h = alloc(3072); short* ck_l = alloc(3072);
  short* cv_t = alloc(3072);
  short* am_h = alloc(6291456); short* am_l = alloc(6291456);
  short* km_h = alloc(1572864); short* km_l = alloc(1572864);
  short* cm_h = alloc(3072); short* cm_l = alloc(3072);

  float* out0 = (float*)d_out;        // [B,N,768]
  float* out1 = out0 + 6291456;       // [B,M,768]
  float* out2 = out1 + 1572864;       // [B,1,768]
  float* out3 = out2 + 3072;          // [B,H,M,N]

  wsplit_t<<<dim3(72, 24), 256, 0, stream>>>(Wqkv, DIM_, QKV_, Wq_h, Wq_l);
  wsplit_t<<<dim3(24, 24), 256, 0, stream>>>(Wout, DIM_, DIM_, Wo_h, Wo_l);

  // Pre-split activations fp32 -> hi/lo bf16. The split buffers alias the
  // am/km/cm workspace, which is dead until the branch kernels run.
  short* xs_h = am_h, *xs_l = am_l;     // [B*N,768]
  short* kxs_h = km_h, *kxs_l = km_l;   // [B*M,768]
  short* cs_h = cm_h, *cs_l = cm_l;     // [B,768]
  fsplit<<<dim3(2048), 256, 0, stream>>>(x, xs_h, xs_l, B_ * N_ * DIM_ / 4);
  fsplit<<<dim3(1536), 256, 0, stream>>>(kx, kxs_h, kxs_l, B_ * M_ * DIM_ / 4);
  fsplit<<<dim3(3), 256, 0, stream>>>(clst, cs_h, cs_l, B_ * DIM_ / 4);

  qkv_mfma<<<dim3(18, 64), 256, 0, stream>>>(xs_h, xs_l, Wq_h, Wq_l, N_,
                                             B_ * N_, tq_h, tq_l, tk_h, tk_l,
                                             tv_t);
  qkv_mfma<<<dim3(18, 16), 256, 0, stream>>>(kxs_h, kxs_l, Wq_h, Wq_l, M_,
                                             B_ * M_, kq_h, kq_l, kk_h, kk_l,
                                             kv_t);
  qkv_mfma<<<dim3(18, 1), 256, 0, stream>>>(cs_h, cs_l, Wq_h, Wq_l, 1, B_,
                                            cq_h, cq_l, ck_h, ck_l, cv_t);

  // Wq_h/Wq_l are dead after the qkv GEMMs; reuse their space for the packed
  // mask (needs 6.29 MB < 7.08 MB). Stream-ordered, so this is safe.
  unsigned* pmask = (unsigned*)Wq_h;
  mask_pack<<<dim3(2048), 256, 0, stream>>>(mask, pmask);

  branch1_mfma<<<dim3(N_ / 32, H_, B_), 512, 0, stream>>>(
      tq_h, tq_l, kk_h, kk_l, kv_t, krd, pmask, out3, am_h, am_l);
  branch2_mfma<<<dim3(M_ / 32, H_, B_), 256, 0, stream>>>(
      kq_h, kq_l, tk_h, tk_l, tv_t, krd, pmask, km_h, km_l);
  branch3_k<<<dim3(H_, B_), 256, 0, stream>>>(cq_h, cq_l, kk_h, kk_l, kv_t,
                                              pmask, cm_h, cm_l);

  proj_mfma<<<dim3(6, 64), 256, 0, stream>>>(am_h, am_l, Wo_h, Wo_l, bout,
                                             out0, B_ * N_);
  proj_mfma<<<dim3(6, 16), 256, 0, stream>>>(km_h, km_l, Wo_h, Wo_l, bout,
                                             out1, B_ * M_);
  proj_mfma<<<dim3(6, 1), 256, 0, stream>>>(cm_h, cm_l, Wo_h, Wo_l, bout,
                                            out2, B_);
}

// Round 4
// 1168.186 us; speedup vs baseline: 1.3342x; 1.0333x over previous
//
#include <hip/hip_runtime.h>
#include <hip/hip_bf16.h>
#include <cmath>
#include <cstdint>

#define B_ 4
#define N_ 2048
#define M_ 512
#define H_ 12
#define D_ 64
#define DIM_ 768
#define QKV_ 2304
#define SCALE_ 0.125f
#define NEG_ -1e9f
#define TEMP_ 24.0f
#define NSPLIT_ 4

typedef __attribute__((ext_vector_type(8))) short bf16x8;
typedef __attribute__((ext_vector_type(4))) float f32x4;

__device__ __forceinline__ short f2bf(float f) {
  union { float f; unsigned u; } v; v.f = f;
  unsigned r = v.u + 0x7fffu + ((v.u >> 16) & 1u);
  return (short)(r >> 16);
}
__device__ __forceinline__ float bf2f(short s) {
  union { unsigned u; float f; } v; v.u = ((unsigned)(unsigned short)s) << 16;
  return v.f;
}
#define MFMA16(a, b, c) __builtin_amdgcn_mfma_f32_16x16x32_bf16(a, b, c, 0, 0, 0)

// Bijective XCD-chunked swizzle (m204): consecutive remapped ids stay on one
// XCD so tiles sharing an A row-panel hit the same L2.
__device__ __forceinline__ int xcd_swizzle(int orig, int nwg) {
  int qd = nwg >> 3, r = nwg & 7;
  int xcd = orig & 7, pos = orig >> 3;
  return (xcd < r ? xcd * (qd + 1) : r * (qd + 1) + (xcd - r) * qd) + pos;
}

// ---------------------------------------------------------------------------
// Transpose + split W [K][Ncols] fp32 -> Wt_h/Wt_l [Ncols][K] bf16.
// ---------------------------------------------------------------------------
__global__ __launch_bounds__(256) void wsplit_t(
    const float* __restrict__ W, int K, int Ncols,
    short* __restrict__ Wt_h, short* __restrict__ Wt_l) {
  __shared__ float t[32][33];
  const int n0 = blockIdx.x * 32, k0 = blockIdx.y * 32;
  const int tid = threadIdx.x;
  for (int e = tid; e < 1024; e += 256) {
    int r = e >> 5, c = e & 31;
    t[r][c] = W[(size_t)(k0 + r) * Ncols + n0 + c];
  }
  __syncthreads();
  for (int e = tid; e < 1024; e += 256) {
    int r = e >> 5, c = e & 31;  // r = n-local, c = k-local
    float f = t[c][r];
    short hi = f2bf(f);
    short lo = f2bf(f - bf2f(hi));
    size_t o = (size_t)(n0 + r) * K + k0 + c;
    Wt_h[o] = hi; Wt_l[o] = lo;
  }
}

// ---------------------------------------------------------------------------
// Elementwise split fp32 -> hi/lo bf16 (vectorized, grid-stride).
// ---------------------------------------------------------------------------
__global__ __launch_bounds__(256) void fsplit(
    const float* __restrict__ in, short* __restrict__ ho,
    short* __restrict__ lo_, int n4) {
  int stride = gridDim.x * 256;
  for (int i = blockIdx.x * 256 + threadIdx.x; i < n4; i += stride) {
    float4 f = ((const float4*)in)[i];
    short h0 = f2bf(f.x), h1 = f2bf(f.y), h2 = f2bf(f.z), h3 = f2bf(f.w);
    short l0 = f2bf(f.x - bf2f(h0)), l1 = f2bf(f.y - bf2f(h1));
    short l2 = f2bf(f.z - bf2f(h2)), l3 = f2bf(f.w - bf2f(h3));
    ((short4*)ho)[i] = make_short4(h0, h1, h2, h3);
    ((short4*)lo_)[i] = make_short4(l0, l1, l2, l3);
  }
}

// ---------------------------------------------------------------------------
// Pack int32 mask [B,H,N,M] -> bitmask [B,H,N,M/32] via wave ballot.
// ---------------------------------------------------------------------------
__global__ __launch_bounds__(256) void mask_pack(
    const int* __restrict__ mask, unsigned* __restrict__ pm) {
  const size_t total = (size_t)B_ * H_ * N_ * M_;
  const size_t stride = (size_t)gridDim.x * blockDim.x;
  const int lane = threadIdx.x & 63;
  for (size_t i = (size_t)blockIdx.x * blockDim.x + threadIdx.x; i < total;
       i += stride) {
    unsigned long long bal = __ballot(mask[i] != 0);
    if (lane == 0) *(unsigned long long*)(pm + (i >> 5)) = bal;
  }
}

// ---------------------------------------------------------------------------
// QKV GEMM (MFMA, split-bf16): A hi/lo bf16 [rows,768] @ Wt^T -> q/k hi/lo
// bf16 [B,H,rows,64] and v transposed bf16 [B,H,64,rows]. Tile 128x128.
// ---------------------------------------------------------------------------
__global__ __launch_bounds__(256) void qkv_mfma(
    const short* __restrict__ Ahp, const short* __restrict__ Alp,
    const short* __restrict__ Wth, const short* __restrict__ Wtl,
    int rowsPerB, int totalRows,
    short* __restrict__ qh, short* __restrict__ ql,
    short* __restrict__ kh, short* __restrict__ kl,
    short* __restrict__ vt) {
  __shared__ __align__(16) short As_h[128 * 40], As_l[128 * 40];
  __shared__ __align__(16) short Bs_h[128 * 40], Bs_l[128 * 40];
  const int nwg = gridDim.x * gridDim.y;
  const int nb = xcd_swizzle(blockIdx.y * gridDim.x + blockIdx.x, nwg);
  const int gx = gridDim.x;
  const int r0 = (nb / gx) * 128, c0 = (nb % gx) * 128;
  const int tid = threadIdx.x;
  const int w = tid >> 6, ln = tid & 63, q = ln >> 4, l15 = ln & 15;
  const int wM = (w & 1) * 64, wN = (w >> 1) * 64;
  const f32x4 z = {0.f, 0.f, 0.f, 0.f};
  f32x4 acc[4][4];
  for (int i = 0; i < 4; i++)
    for (int j = 0; j < 4; j++) acc[i][j] = z;
  for (int k0 = 0; k0 < DIM_; k0 += 32) {
    for (int e = tid; e < 512; e += 256) {
      int row = e >> 2, c = e & 3;
      int ar = r0 + row; if (ar >= totalRows) ar = totalRows - 1;
      size_t ga = (size_t)ar * DIM_ + k0 + c * 8;
      size_t gb = (size_t)(c0 + row) * DIM_ + k0 + c * 8;
      int o = row * 40 + c * 8;
      *(uint4*)(As_h + o) = *(const uint4*)(Ahp + ga);
      *(uint4*)(As_l + o) = *(const uint4*)(Alp + ga);
      *(uint4*)(Bs_h + o) = *(const uint4*)(Wth + gb);
      *(uint4*)(Bs_l + o) = *(const uint4*)(Wtl + gb);
    }
    __syncthreads();
    bf16x8 ah[4], al[4], bhf[4], blf[4];
    for (int mt = 0; mt < 4; mt++) {
      int o = (wM + mt * 16 + l15) * 40 + q * 8;
      ah[mt] = *(const bf16x8*)(As_h + o);
      al[mt] = *(const bf16x8*)(As_l + o);
    }
    for (int nt = 0; nt < 4; nt++) {
      int o = (wN + nt * 16 + l15) * 40 + q * 8;
      bhf[nt] = *(const bf16x8*)(Bs_h + o);
      blf[nt] = *(const bf16x8*)(Bs_l + o);
    }
    for (int mt = 0; mt < 4; mt++)
      for (int nt = 0; nt < 4; nt++) {
        f32x4 c = acc[mt][nt];
        c = MFMA16(ah[mt], bhf[nt], c);
        c = MFMA16(ah[mt], blf[nt], c);
        c = MFMA16(al[mt], bhf[nt], c);
        acc[mt][nt] = c;
      }
    __syncthreads();
  }
  for (int mt = 0; mt < 4; mt++)
    for (int nt = 0; nt < 4; nt++)
      for (int r = 0; r < 4; r++) {
        int gr = r0 + wM + mt * 16 + q * 4 + r;
        if (gr >= totalRows) continue;
        int gc = c0 + wN + nt * 16 + l15;
        int which = gc / DIM_;
        int rem = gc - which * DIM_;
        int hh = rem >> 6, d = rem & 63;
        int b = gr / rowsPerB, n = gr - b * rowsPerB;
        float v = acc[mt][nt][r];
        short hi = f2bf(v);
        if (which == 2) {
          vt[(((size_t)b * H_ + hh) * 64 + d) * rowsPerB + n] = hi;
        } else {
          short lo = f2bf(v - bf2f(hi));
          size_t o = (((size_t)b * H_ + hh) * rowsPerB + n) * 64 + d;
          if (which == 0) { qh[o] = hi; ql[o] = lo; }
          else           { kh[o] = hi; kl[o] = lo; }
        }
      }
}

// ---------------------------------------------------------------------------
// Output projection (MFMA, split-bf16): A hi/lo bf16 [rows,768] @ Wot^T + b.
// ---------------------------------------------------------------------------
__global__ __launch_bounds__(256) void proj_mfma(
    const short* __restrict__ Ahp, const short* __restrict__ Alp,
    const short* __restrict__ Bth, const short* __restrict__ Btl,
    const float* __restrict__ bias, float* __restrict__ C, int totalRows) {
  __shared__ __align__(16) short As_h[128 * 40], As_l[128 * 40];
  __shared__ __align__(16) short Bs_h[128 * 40], Bs_l[128 * 40];
  const int nwg = gridDim.x * gridDim.y;
  const int nb = xcd_swizzle(blockIdx.y * gridDim.x + blockIdx.x, nwg);
  const int gx = gridDim.x;
  const int r0 = (nb / gx) * 128, c0 = (nb % gx) * 128;
  const int tid = threadIdx.x;
  const int w = tid >> 6, ln = tid & 63, q = ln >> 4, l15 = ln & 15;
  const int wM = (w & 1) * 64, wN = (w >> 1) * 64;
  const f32x4 z = {0.f, 0.f, 0.f, 0.f};
  f32x4 acc[4][4];
  for (int i = 0; i < 4; i++)
    for (int j = 0; j < 4; j++) acc[i][j] = z;
  for (int k0 = 0; k0 < DIM_; k0 += 32) {
    for (int e = tid; e < 512; e += 256) {
      int row = e >> 2, c = e & 3;
      int ar = r0 + row; if (ar >= totalRows) ar = totalRows - 1;
      size_t ga = (size_t)ar * DIM_ + k0 + c * 8;
      size_t gb = (size_t)(c0 + row) * DIM_ + k0 + c * 8;
      int o = row * 40 + c * 8;
      *(uint4*)(As_h + o) = *(const uint4*)(Ahp + ga);
      *(uint4*)(As_l + o) = *(const uint4*)(Alp + ga);
      *(uint4*)(Bs_h + o) = *(const uint4*)(Bth + gb);
      *(uint4*)(Bs_l + o) = *(const uint4*)(Btl + gb);
    }
    __syncthreads();
    bf16x8 ah[4], al[4], bhf[4], blf[4];
    for (int mt = 0; mt < 4; mt++) {
      int o = (wM + mt * 16 + l15) * 40 + q * 8;
      ah[mt] = *(const bf16x8*)(As_h + o);
      al[mt] = *(const bf16x8*)(As_l + o);
    }
    for (int nt = 0; nt < 4; nt++) {
      int o = (wN + nt * 16 + l15) * 40 + q * 8;
      bhf[nt] = *(const bf16x8*)(Bs_h + o);
      blf[nt] = *(const bf16x8*)(Bs_l + o);
    }
    for (int mt = 0; mt < 4; mt++)
      for (int nt = 0; nt < 4; nt++) {
        f32x4 c = acc[mt][nt];
        c = MFMA16(ah[mt], bhf[nt], c);
        c = MFMA16(ah[mt], blf[nt], c);
        c = MFMA16(al[mt], bhf[nt], c);
        acc[mt][nt] = c;
      }
    __syncthreads();
  }
  for (int mt = 0; mt < 4; mt++)
    for (int nt = 0; nt < 4; nt++)
      for (int r = 0; r < 4; r++) {
        int gr = r0 + wM + mt * 16 + q * 4 + r;
        if (gr >= totalRows) continue;
        int gc = c0 + wN + nt * 16 + l15;
        C[(size_t)gr * DIM_ + gc] = acc[mt][nt][r] + bias[gc];
      }
}

// ---------------------------------------------------------------------------
// Branch 1 (MFMA): per (b,h,32 n-rows), 512 threads / 8 waves.
// ---------------------------------------------------------------------------
__global__ __launch_bounds__(512, 4) void branch1_mfma(
    const short* __restrict__ tqh, const short* __restrict__ tql,
    const short* __restrict__ kkh, const short* __restrict__ kkl,
    const short* __restrict__ kvt, const float* __restrict__ krd,
    const unsigned* __restrict__ pm, float* __restrict__ out3,
    short* __restrict__ amh, short* __restrict__ aml) {
  __shared__ __align__(16) float sc[32 * 520];  // 66560 B, aliased by P2h/P2l
  __shared__ unsigned mskw[512];                // 32 rows x 16 words
  __shared__ float rowM[32], inv1[32], inv2[32];
  short* P2h = (short*)sc;          // [32][520]
  short* P2l = P2h + 32 * 520;
  const int b = blockIdx.z, h = blockIdx.y, n0 = blockIdx.x * 32;
  const size_t bhi = (size_t)b * H_ + h;
  const int tid = threadIdx.x;
  const int w = tid >> 6, ln = tid & 63, q = ln >> 4, l15 = ln & 15;
  const float* krd0 = krd + bhi * M_ * N_;
  mskw[tid] = pm[(bhi * N_ + n0) * 16 + tid];
  // ---- QK^T: 32n x 512m, wave w -> ct in [4w, 4w+4) ----
  {
    bf16x8 ah[2][2], al[2][2];
    for (int mt = 0; mt < 2; mt++) {
      const short* ap = tqh + ((bhi * N_ + n0 + mt * 16 + l15) * D_ + q * 8);
      const short* ap2 = tql + ((bhi * N_ + n0 + mt * 16 + l15) * D_ + q * 8);
      ah[mt][0] = *(const bf16x8*)(ap);
      ah[mt][1] = *(const bf16x8*)(ap + 32);
      al[mt][0] = *(const bf16x8*)(ap2);
      al[mt][1] = *(const bf16x8*)(ap2 + 32);
    }
    for (int t = 0; t < 4; t++) {
      int ct = w * 4 + t;
      const short* bp = kkh + ((bhi * M_ + ct * 16 + l15) * D_ + q * 8);
      const short* bp2 = kkl + ((bhi * M_ + ct * 16 + l15) * D_ + q * 8);
      bf16x8 bh0 = *(const bf16x8*)(bp);
      bf16x8 bh1 = *(const bf16x8*)(bp + 32);
      bf16x8 bl0 = *(const bf16x8*)(bp2);
      bf16x8 bl1 = *(const bf16x8*)(bp2 + 32);
      for (int mt = 0; mt < 2; mt++) {
        f32x4 a = {0.f, 0.f, 0.f, 0.f};
        a = MFMA16(ah[mt][0], bh0, a); a = MFMA16(ah[mt][1], bh1, a);
        a = MFMA16(ah[mt][0], bl0, a); a = MFMA16(ah[mt][1], bl1, a);
        a = MFMA16(al[mt][0], bh0, a); a = MFMA16(al[mt][1], bh1, a);
        for (int r = 0; r < 4; r++) {
          int row = mt * 16 + q * 4 + r;
          sc[row * 520 + ((ct * 16 + l15) ^ ((row >> 2) & 7))] = a[r];
        }
      }
    }
  }
  // ---- prefetch krd for P-build (latency hides under stats phase) ----
  const int pi = tid & 31, pg = tid >> 5;
  float kr[32];
#pragma unroll
  for (int t = 0; t < 32; t++)
    kr[t] = __builtin_nontemporal_load(
        krd0 + (size_t)(pg * 32 + t) * N_ + n0 + pi);
  __syncthreads();
  // ---- mask + scale + row stats; sc ends holding e2 = exp(dv - mx) ----
  {
    int i = tid >> 4, jl = tid & 15;
    int sw = (i >> 2) & 7;
    float* scr = sc + i * 520;
    const unsigned* mrow = mskw + i * 16;
    float mx = -INFINITY;
    for (int j = jl; j < M_; j += 16) {
      float dv = scr[j ^ sw];
      dv = ((mrow[j >> 5] >> (j & 31)) & 1) ? NEG_ : dv * SCALE_;
      scr[j ^ sw] = dv;
      mx = fmaxf(mx, dv);
    }
    for (int o = 8; o >= 1; o >>= 1) mx = fmaxf(mx, __shfl_xor(mx, o, 16));
    float s1 = 0.f, s2 = 0.f;
    for (int j = jl; j < M_; j += 16) {
      float e2 = __expf(scr[j ^ sw] - mx);
      scr[j ^ sw] = e2;
      float x2 = e2 * e2, x4 = x2 * x2, x8 = x4 * x4, x16 = x8 * x8;
      s1 += x16 * x8;   // e2^24
      s2 += e2;
    }
    for (int o = 8; o >= 1; o >>= 1) {
      s1 += __shfl_xor(s1, o, 16);
      s2 += __shfl_xor(s2, o, 16);
    }
    if (jl == 0) { inv1[i] = 1.f / s1; inv2[i] = 1.f / s2; }
  }
  __syncthreads();
  // ---- P build: out3 write + P2 hi/lo (overlay sc via register staging) ----
  {
    float rv[32];
    int sw2 = (pi >> 2) & 7;
#pragma unroll
    for (int t = 0; t < 32; t++)
      rv[t] = sc[pi * 520 + ((pg * 32 + t) ^ sw2)];
    __syncthreads();
    float v1 = inv1[pi], v2 = inv2[pi];
    float* o3 = out3 + bhi * M_ * N_ + n0 + pi;
#pragma unroll
    for (int t = 0; t < 32; t += 2) {
      int j = pg * 32 + t;
      float e2a = rv[t], e2b = rv[t + 1];
      float a2 = e2a * e2a, a4 = a2 * a2, a8 = a4 * a4, a16 = a8 * a8;
      float b2 = e2b * e2b, b4 = b2 * b2, b8 = b4 * b4, b16 = b8 * b8;
      __builtin_nontemporal_store(a16 * a8 * v1 * kr[t], o3 + (size_t)j * N_);
      __builtin_nontemporal_store(b16 * b8 * v1 * kr[t + 1],
                                  o3 + (size_t)(j + 1) * N_);
      float p0 = e2a * v2 * kr[t];
      float p1 = e2b * v2 * kr[t + 1];
      short h0 = f2bf(p0), h1 = f2bf(p1);
      short lo0 = f2bf(p0 - bf2f(h0)), lo1 = f2bf(p1 - bf2f(h1));
      *(short2*)(P2h + pi * 520 + j) = make_short2(h0, h1);
      *(short2*)(P2l + pi * 520 + j) = make_short2(lo0, lo1);
    }
  }
  __syncthreads();
  // ---- PV: wave w -> (n-half, d-chunk) ----
  {
    const int dc = w & 3, nh = w >> 2;
    f32x4 o0 = {0.f, 0.f, 0.f, 0.f}, o1 = {0.f, 0.f, 0.f, 0.f};
    const short* vbase = kvt + ((bhi * 64 + dc * 16 + l15) * (size_t)M_ + q * 8);
    const short* ph = P2h + (nh * 16 + l15) * 520 + q * 8;
    const short* pl = P2l + (nh * 16 + l15) * 520 + q * 8;
    for (int kc = 0; kc < 16; kc += 2) {
      bf16x8 pa0 = *(const bf16x8*)(ph + kc * 32);
      bf16x8 pl0 = *(const bf16x8*)(pl + kc * 32);
      bf16x8 bv0 = *(const bf16x8*)(vbase + kc * 32);
      o0 = MFMA16(pa0, bv0, o0);
      o0 = MFMA16(pl0, bv0, o0);
      bf16x8 pa1 = *(const bf16x8*)(ph + (kc + 1) * 32);
      bf16x8 pl1 = *(const bf16x8*)(pl + (kc + 1) * 32);
      bf16x8 bv1 = *(const bf16x8*)(vbase + (kc + 1) * 32);
      o1 = MFMA16(pa1, bv1, o1);
      o1 = MFMA16(pl1, bv1, o1);
    }
    o0 += o1;
    for (int r = 0; r < 4; r++) {
      float v = o0[r];
      short hi = f2bf(v), lo = f2bf(v - bf2f(hi));
      size_t o = ((size_t)b * N_ + n0 + nh * 16 + q * 4 + r) * DIM_ +
                 h * 64 + dc * 16 + l15;
      amh[o] = hi; aml[o] = lo;
    }
  }
}

// ---------------------------------------------------------------------------
// Branch 2 (MFMA, flash, split-N): per (b,h,32 m-rows, n-quarter of 512).
// Each split writes UNNORMALIZED partials (oa, rowM, rowL); b2_combine merges.
// ---------------------------------------------------------------------------
__global__ __launch_bounds__(256) void branch2_mfma(
    const short* __restrict__ kqh, const short* __restrict__ kql,
    const short* __restrict__ tkh, const short* __restrict__ tkl,
    const short* __restrict__ tvt, const float* __restrict__ krd,
    const unsigned* __restrict__ pm, float* __restrict__ pO,
    float* __restrict__ pML) {
  __shared__ __align__(16) float sc[32 * 136];  // 17408 B, aliased by P2h/P2l
  __shared__ unsigned mskw[128];
  __shared__ float rowM[32], rowL[32], alph[32];
  short* P2h = (short*)sc;          // [32][136]
  short* P2l = P2h + 32 * 136;
  const int b = blockIdx.z, h = blockIdx.y;
  const int mblk = blockIdx.x >> 2, split = blockIdx.x & 3;
  const int m0 = mblk * 32;
  const size_t bhi = (size_t)b * H_ + h;
  const int pidx = ((int)bhi * 16 + mblk) * NSPLIT_ + split;
  const int tid = threadIdx.x;
  const int w = tid >> 6, ln = tid & 63, q = ln >> 4, l15 = ln & 15;
  const float* krd0 = krd + (bhi * M_ + m0) * N_;
  const int mword = m0 >> 5;
  bf16x8 Ah[2][2], Al[2][2];
  for (int mt = 0; mt < 2; mt++)
    for (int kc = 0; kc < 2; kc++) {
      size_t o = (bhi * M_ + m0 + mt * 16 + l15) * D_ + kc * 32 + q * 8;
      Ah[mt][kc] = *(const bf16x8*)(kqh + o);
      Al[mt][kc] = *(const bf16x8*)(kql + o);
    }
  if (tid < 32) { rowM[tid] = -INFINITY; rowL[tid] = 0.f; }
  const f32x4 z = {0.f, 0.f, 0.f, 0.f};
  f32x4 oa[2]; oa[0] = z; oa[1] = z;
  __syncthreads();
  const int nbeg = split * (N_ / NSPLIT_), nend = nbeg + N_ / NSPLIT_;
  for (int n0 = nbeg; n0 < nend; n0 += 128) {
    if (tid < 128) mskw[tid] = pm[(bhi * N_ + n0 + tid) * 16 + mword];
    for (int t = 0; t < 2; t++) {  // QK: wave w -> ct = 2w+t
      int ct = w * 2 + t;
      const short* bp = tkh + ((bhi * N_ + n0 + ct * 16 + l15) * D_ + q * 8);
      const short* bp2 = tkl + ((bhi * N_ + n0 + ct * 16 + l15) * D_ + q * 8);
      bf16x8 bh0 = *(const bf16x8*)(bp), bh1 = *(const bf16x8*)(bp + 32);
      bf16x8 bl0 = *(const bf16x8*)(bp2), bl1 = *(const bf16x8*)(bp2 + 32);
      for (int mt = 0; mt < 2; mt++) {
        f32x4 a = {0.f, 0.f, 0.f, 0.f};
        a = MFMA16(Ah[mt][0], bh0, a); a = MFMA16(Ah[mt][1], bh1, a);
        a = MFMA16(Ah[mt][0], bl0, a); a = MFMA16(Ah[mt][1], bl1, a);
        a = MFMA16(Al[mt][0], bh0, a); a = MFMA16(Al[mt][1], bh1, a);
        for (int r = 0; r < 4; r++)
          sc[(mt * 16 + q * 4 + r) * 136 + ct * 16 + l15] = a[r];
      }
    }
    __syncthreads();
    {  // online softmax: 8 threads/row
      int i = tid >> 3, jl = tid & 7;
      float mx = -INFINITY;
      for (int j = jl; j < 128; j += 8) {
        float s = sc[i * 136 + j];
        s = ((mskw[j] >> i) & 1) ? NEG_ : s * SCALE_;
        sc[i * 136 + j] = s;
        mx = fmaxf(mx, s);
      }
      for (int o = 4; o >= 1; o >>= 1) mx = fmaxf(mx, __shfl_xor(mx, o, 8));
      float mold = rowM[i];
      float mnew = fmaxf(mold, mx);
      float sum = 0.f;
      for (int j = jl; j < 128; j += 8) {
        float p = __expf(sc[i * 136 + j] - mnew);
        sc[i * 136 + j] = p;
        sum += p;
      }
      for (int o = 4; o >= 1; o >>= 1) sum += __shfl_xor(sum, o, 8);
      if (jl == 0) {
        float al = (mold == -INFINITY) ? 0.f : __expf(mold - mnew);
        alph[i] = al;
        rowL[i] = rowL[i] * al + sum;
        rowM[i] = mnew;
      }
    }
    __syncthreads();
    {  // P2 = p * krd, hi/lo (overlay sc via register staging)
      float rv[16], kv2[16];
      const int j = tid & 127;
      const int ib = tid >> 7;
#pragma unroll
      for (int t = 0; t < 16; t++) {
        rv[t] = sc[(ib + 2 * t) * 136 + j];
        kv2[t] = __builtin_nontemporal_load(
            krd0 + (size_t)(ib + 2 * t) * N_ + n0 + j);
      }
      __syncthreads();
#pragma unroll
      for (int t = 0; t < 16; t++) {
        int i = ib + 2 * t;
        float p2 = rv[t] * kv2[t];
        short hi = f2bf(p2), lo = f2bf(p2 - bf2f(hi));
        P2h[i * 136 + j] = hi;
        P2l[i * 136 + j] = lo;
      }
    }
    __syncthreads();
    {  // PV accumulate, wave w -> dc = w
      for (int mt = 0; mt < 2; mt++) {
        f32x4 t = oa[mt];
        for (int r = 0; r < 4; r++) t[r] *= alph[mt * 16 + q * 4 + r];
        for (int kc = 0; kc < 4; kc++) {
          bf16x8 pa = *(const bf16x8*)(P2h + (mt * 16 + l15) * 136 + kc * 32 + q * 8);
          bf16x8 pl = *(const bf16x8*)(P2l + (mt * 16 + l15) * 136 + kc * 32 + q * 8);
          bf16x8 bv = *(const bf16x8*)(tvt + ((bhi * 64 + w * 16 + l15) * (size_t)N_ + n0 + kc * 32 + q * 8));
          t = MFMA16(pa, bv, t);
          t = MFMA16(pl, bv, t);
        }
        oa[mt] = t;
      }
    }
    __syncthreads();
  }
  // write unnormalized partials
  float* po = pO + (size_t)pidx * 2048;
  for (int mt = 0; mt < 2; mt++)
    for (int r = 0; r < 4; r++) {
      int row = mt * 16 + q * 4 + r;
      po[row * 64 + w * 16 + l15] = oa[mt][r];
    }
  if (tid < 32) {
    pML[(size_t)pidx * 64 + tid] = rowM[tid];
    pML[(size_t)pidx * 64 + 32 + tid] = rowL[tid];
  }
}

// ---------------------------------------------------------------------------
// Flash merge of branch2's NSPLIT partials -> km hi/lo bf16.
// ---------------------------------------------------------------------------
__global__ __launch_bounds__(256) void b2_combine(
    const float* __restrict__ pO, const float* __restrict__ pML,
    short* __restrict__ kmh, short* __restrict__ kml) {
  const int mblk = blockIdx.x, h = blockIdx.y, b = blockIdx.z;
  const size_t bhi = (size_t)b * H_ + h;
  const int base = ((int)bhi * 16 + mblk) * NSPLIT_;
  __shared__ float mS[NSPLIT_][32], lS[NSPLIT_][32], wgt[NSPLIT_][32], invL[32];
  const int tid = threadIdx.x;
  if (tid < 32 * NSPLIT_) {
    int s = tid >> 5, r = tid & 31;
    mS[s][r] = pML[(size_t)(base + s) * 64 + r];
    lS[s][r] = pML[(size_t)(base + s) * 64 + 32 + r];
  }
  __syncthreads();
  if (tid < 32) {
    float Mv = mS[0][tid];
    for (int s = 1; s < NSPLIT_; s++) Mv = fmaxf(Mv, mS[s][tid]);
    float L = 0.f;
    for (int s = 0; s < NSPLIT_; s++) {
      float wv = __expf(mS[s][tid] - Mv);
      wgt[s][tid] = wv;
      L += lS[s][tid] * wv;
    }
    invL[tid] = 1.f / L;
  }
  __syncthreads();
  const int row = tid >> 3, c0 = (tid & 7) * 8;
  float acc[8] = {0, 0, 0, 0, 0, 0, 0, 0};
  for (int s = 0; s < NSPLIT_; s++) {
    float wv = wgt[s][row];
    const float* src = pO + (size_t)(base + s) * 2048 + row * 64 + c0;
    float4 a = *(const float4*)(src);
    float4 bq = *(const float4*)(src + 4);
    acc[0] += a.x * wv;  acc[1] += a.y * wv;
    acc[2] += a.z * wv;  acc[3] += a.w * wv;
    acc[4] += bq.x * wv; acc[5] += bq.y * wv;
    acc[6] += bq.z * wv; acc[7] += bq.w * wv;
  }
  float il = invL[row];
  size_t o = ((size_t)b * M_ + mblk * 32 + row) * DIM_ + h * 64 + c0;
#pragma unroll
  for (int e = 0; e < 8; e++) {
    float v = acc[e] * il;
    short hi = f2bf(v), lo = f2bf(v - bf2f(hi));
    kmh[o + e] = hi; kml[o + e] = lo;
  }
}

// ---------------------------------------------------------------------------
// Branch 3: cluster query per (b,h), vector math from hi/lo inputs.
// ---------------------------------------------------------------------------
__global__ __launch_bounds__(256) void branch3_k(
    const short* __restrict__ cqh, const short* __restrict__ cql,
    const short* __restrict__ kkh, const short* __restrict__ kkl,
    const short* __restrict__ kvt, const unsigned* __restrict__ pm,
    short* __restrict__ cmh, short* __restrict__ cml) {
  const int h = blockIdx.x, b = blockIdx.y;
  __shared__ float qv[64];
  __shared__ float p[512];
  __shared__ float wr1[4], wr2[4];
  __shared__ float ored[4][64];
  const size_t bhi = (size_t)b * H_ + h;
  const int tid = threadIdx.x;
  if (tid < 64) qv[tid] = bf2f(cqh[bhi * 64 + tid]) + bf2f(cql[bhi * 64 + tid]);
  __syncthreads();
  const unsigned* m0p = pm + bhi * N_ * 16;  // row n = 0
  for (int j = tid; j < 512; j += 256) {
    float acc = 0;
    for (int kk = 0; kk < 64; kk++)
      acc += qv[kk] * (bf2f(kkh[(bhi * M_ + j) * 64 + kk]) +
                       bf2f(kkl[(bhi * M_ + j) * 64 + kk]));
    acc *= SCALE_;
    if ((m0p[j >> 5] >> (j & 31)) & 1) acc = NEG_;
    p[j] = acc;
  }
  __syncthreads();
  float mx = fmaxf(p[tid], p[tid + 256]);
  for (int o = 32; o >= 1; o >>= 1) mx = fmaxf(mx, __shfl_xor(mx, o, 64));
  if ((tid & 63) == 0) wr1[tid >> 6] = mx;
  __syncthreads();
  mx = fmaxf(fmaxf(wr1[0], wr1[1]), fmaxf(wr1[2], wr1[3]));
  float e0 = __expf(p[tid] - mx), e1 = __expf(p[tid + 256] - mx);
  float s = e0 + e1;
  for (int o = 32; o >= 1; o >>= 1) s += __shfl_xor(s, o, 64);
  p[tid] = e0; p[tid + 256] = e1;
  if ((tid & 63) == 0) wr2[tid >> 6] = s;
  __syncthreads();
  float invS = 1.f / (wr2[0] + wr2[1] + wr2[2] + wr2[3]);
  int dd = tid & 63, gg = tid >> 6;
  float o = 0;
  for (int j = gg; j < 512; j += 4)
    o += p[j] * bf2f(kvt[(bhi * 64 + dd) * (size_t)M_ + j]);
  ored[gg][dd] = o;
  __syncthreads();
  if (gg == 0) {
    float r = (ored[0][dd] + ored[1][dd] + ored[2][dd] + ored[3][dd]) * invS;
    short hi = f2bf(r), lo = f2bf(r - bf2f(hi));
    cmh[(size_t)b * DIM_ + h * 64 + dd] = hi;
    cml[(size_t)b * DIM_ + h * 64 + dd] = lo;
  }
}

// ---------------------------------------------------------------------------
extern "C" void kernel_launch(void* const* d_in, const int* in_sizes, int n_in,
                              void* d_out, int out_size, void* d_ws,
                              size_t ws_size, hipStream_t stream) {
  const float* x = (const float*)d_in[0];
  const float* kx = (const float*)d_in[1];
  const float* krd = (const float*)d_in[2];
  const float* clst = (const float*)d_in[3];
  const int* mask = (const int*)d_in[4];
  const float* Wqkv = (const float*)d_in[5];
  const float* Wout = (const float*)d_in[6];
  const float* bout = (const float*)d_in[7];

  short* p = (short*)d_ws;
  auto alloc = [&](size_t n) { short* r = p; p += n; return r; };
  short* Wq_h = alloc(2304ull * 768); short* Wq_l = alloc(2304ull * 768);
  short* Wo_h = alloc(768ull * 768);  short* Wo_l = alloc(768ull * 768);
  short* tq_h = alloc(6291456); short* tq_l = alloc(6291456);
  short* tk_h = alloc(6291456); short* tk_l = alloc(6291456);
  short* tv_t = alloc(6291456);
  short* kq_h = alloc(1572864); short* kq_l = alloc(1572864);
  short* kk_h = alloc(1572864); short* kk_l = alloc(1572864);
  short* kv_t = alloc(1572864);
  short* cq_h = alloc(3072); short* cq_l = alloc(3072);
  short* ck_h = alloc(3072); short* ck_l = alloc(3072);
  short* cv_t = alloc(3072);
  short* am_h = alloc(6291456); short* am_l = alloc(6291456);
  short* km_h = alloc(1572864); short* km_l = alloc(1572864);
  short* cm_h = alloc(3072); short* cm_l = alloc(3072);

  float* out0 = (float*)d_out;        // [B,N,768]
  float* out1 = out0 + 6291456;       // [B,M,768]
  float* out2 = out1 + 1572864;       // [B,1,768]
  float* out3 = out2 + 3072;          // [B,H,M,N]

  wsplit_t<<<dim3(72, 24), 256, 0, stream>>>(Wqkv, DIM_, QKV_, Wq_h, Wq_l);
  wsplit_t<<<dim3(24, 24), 256, 0, stream>>>(Wout, DIM_, DIM_, Wo_h, Wo_l);

  // Pre-split activations fp32 -> hi/lo bf16. The split buffers alias the
  // am/km/cm workspace, which is dead until the branch kernels run.
  short* xs_h = am_h, *xs_l = am_l;     // [B*N,768]
  short* kxs_h = km_h, *kxs_l = km_l;   // [B*M,768]
  short* cs_h = cm_h, *cs_l = cm_l;     // [B,768]
  fsplit<<<dim3(2048), 256, 0, stream>>>(x, xs_h, xs_l, B_ * N_ * DIM_ / 4);
  fsplit<<<dim3(1536), 256, 0, stream>>>(kx, kxs_h, kxs_l, B_ * M_ * DIM_ / 4);
  fsplit<<<dim3(3), 256, 0, stream>>>(clst, cs_h, cs_l, B_ * DIM_ / 4);

  qkv_mfma<<<dim3(18, 64), 256, 0, stream>>>(xs_h, xs_l, Wq_h, Wq_l, N_,
                                             B_ * N_, tq_h, tq_l, tk_h, tk_l,
                                             tv_t);
  qkv_mfma<<<dim3(18, 16), 256, 0, stream>>>(kxs_h, kxs_l, Wq_h, Wq_l, M_,
                                             B_ * M_, kq_h, kq_l, kk_h, kk_l,
                                             kv_t);
  qkv_mfma<<<dim3(18, 1), 256, 0, stream>>>(cs_h, cs_l, Wq_h, Wq_l, 1, B_,
                                            cq_h, cq_l, ck_h, ck_l, cv_t);

  // Wq_h/Wq_l are dead after the qkv GEMMs; reuse their space for the packed
  // mask (needs 6.29 MB < 7.08 MB). Stream-ordered, so this is safe.
  unsigned* pmask = (unsigned*)Wq_h;
  mask_pack<<<dim3(2048), 256, 0, stream>>>(mask, pmask);

  branch1_mfma<<<dim3(N_ / 32, H_, B_), 512, 0, stream>>>(
      tq_h, tq_l, kk_h, kk_l, kv_t, krd, pmask, out3, am_h, am_l);

  // Branch2 partials live in out0/out1 (d_out), which proj overwrites later.
  float* pO = out0;                   // 3072 x 2048 f32 = 25.2 MB (== out0)
  float* pML = out1;                  // 3072 x 64 f32 = 0.79 MB (< out1)
  branch2_mfma<<<dim3((M_ / 32) * NSPLIT_, H_, B_), 256, 0, stream>>>(
      kq_h, kq_l, tk_h, tk_l, tv_t, krd, pmask, pO, pML);
  b2_combine<<<dim3(M_ / 32, H_, B_), 256, 0, stream>>>(pO, pML, km_h, km_l);

  branch3_k<<<dim3(H_, B_), 256, 0, stream>>>(cq_h, cq_l, kk_h, kk_l, kv_t,
                                              pmask, cm_h, cm_l);

  proj_mfma<<<dim3(6, 64), 256, 0, stream>>>(am_h, am_l, Wo_h, Wo_l, bout,
                                             out0, B_ * N_);
  proj_mfma<<<dim3(6, 16), 256, 0, stream>>>(km_h, km_l, Wo_h, Wo_l, bout,
                                             out1, B_ * M_);
  proj_mfma<<<dim3(6, 1), 256, 0, stream>>>(cm_h, cm_l, Wo_h, Wo_l, bout,
                                            out2, B_);
}

// Round 5
// 975.311 us; speedup vs baseline: 1.5981x; 1.1978x over previous
//
#include <hip/hip_runtime.h>
#include <hip/hip_bf16.h>
#include <cmath>
#include <cstdint>

#define B_ 4
#define N_ 2048
#define M_ 512
#define H_ 12
#define D_ 64
#define DIM_ 768
#define QKV_ 2304
#define SCALE_ 0.125f
#define NEG_ -1e9f
#define TEMP_ 24.0f
#define NSPLIT_ 8

typedef __attribute__((ext_vector_type(8))) short bf16x8;
typedef __attribute__((ext_vector_type(4))) float f32x4;

__device__ __forceinline__ short f2bf(float f) {
  union { float f; unsigned u; } v; v.f = f;
  unsigned r = v.u + 0x7fffu + ((v.u >> 16) & 1u);
  return (short)(r >> 16);
}
__device__ __forceinline__ float bf2f(short s) {
  union { unsigned u; float f; } v; v.u = ((unsigned)(unsigned short)s) << 16;
  return v.f;
}
#define MFMA16(a, b, c) __builtin_amdgcn_mfma_f32_16x16x32_bf16(a, b, c, 0, 0, 0)

// Async global->LDS, 16B per lane. LDS dest is wave-uniform base + lane*16,
// which our tid-linear staging mapping satisfies exactly.
__device__ __forceinline__ void gl16(const void* g, void* l) {
  __builtin_amdgcn_global_load_lds(
      (const __attribute__((address_space(1))) unsigned int*)g,
      (__attribute__((address_space(3))) unsigned int*)l, 16, 0, 0);
}

// Bijective XCD-chunked swizzle (m204).
__device__ __forceinline__ int xcd_swizzle(int orig, int nwg) {
  int qd = nwg >> 3, r = nwg & 7;
  int xcd = orig & 7, pos = orig >> 3;
  return (xcd < r ? xcd * (qd + 1) : r * (qd + 1) + (xcd - r) * qd) + pos;
}

// ---------------------------------------------------------------------------
// Both weight transposes+splits in one launch. x<72: Wqkv, else Wout.
// ---------------------------------------------------------------------------
__global__ __launch_bounds__(256) void wsplit_all(
    const float* __restrict__ Wqkv, const float* __restrict__ Wout,
    short* __restrict__ Wqh, short* __restrict__ Wql,
    short* __restrict__ Woh, short* __restrict__ Wol) {
  __shared__ float t[32][33];
  int bx = blockIdx.x;
  const float* W; int Ncols; short *Wh, *Wl;
  if (bx < 72) { W = Wqkv; Ncols = QKV_; Wh = Wqh; Wl = Wql; }
  else { bx -= 72; W = Wout; Ncols = DIM_; Wh = Woh; Wl = Wol; }
  const int K = DIM_;
  const int n0 = bx * 32, k0 = blockIdx.y * 32;
  const int tid = threadIdx.x;
  for (int e = tid; e < 1024; e += 256) {
    int r = e >> 5, c = e & 31;
    t[r][c] = W[(size_t)(k0 + r) * Ncols + n0 + c];
  }
  __syncthreads();
  for (int e = tid; e < 1024; e += 256) {
    int r = e >> 5, c = e & 31;
    float f = t[c][r];
    short hi = f2bf(f);
    short lo = f2bf(f - bf2f(hi));
    size_t o = (size_t)(n0 + r) * K + k0 + c;
    Wh[o] = hi; Wl[o] = lo;
  }
}

// ---------------------------------------------------------------------------
// All three activation splits (x, kx, clst) in one grid-stride launch.
// ---------------------------------------------------------------------------
__global__ __launch_bounds__(256) void fsplit_all(
    const float* __restrict__ x, const float* __restrict__ kx,
    const float* __restrict__ c,
    short* __restrict__ xh, short* __restrict__ xl,
    short* __restrict__ kh2, short* __restrict__ kl2,
    short* __restrict__ ch, short* __restrict__ cl) {
  const int XN4 = B_ * N_ * DIM_ / 4;
  const int KN4 = B_ * M_ * DIM_ / 4;
  const int CN4 = B_ * DIM_ / 4;
  const int total = XN4 + KN4 + CN4;
  int stride = gridDim.x * 256;
  for (int i = blockIdx.x * 256 + threadIdx.x; i < total; i += stride) {
    const float* src; short *ho, *lo2; int idx;
    if (i < XN4) { src = x; ho = xh; lo2 = xl; idx = i; }
    else if (i < XN4 + KN4) { src = kx; ho = kh2; lo2 = kl2; idx = i - XN4; }
    else { src = c; ho = ch; lo2 = cl; idx = i - XN4 - KN4; }
    float4 f = ((const float4*)src)[idx];
    short h0 = f2bf(f.x), h1 = f2bf(f.y), h2 = f2bf(f.z), h3 = f2bf(f.w);
    short l0 = f2bf(f.x - bf2f(h0)), l1 = f2bf(f.y - bf2f(h1));
    short l2 = f2bf(f.z - bf2f(h2)), l3 = f2bf(f.w - bf2f(h3));
    ((short4*)ho)[idx] = make_short4(h0, h1, h2, h3);
    ((short4*)lo2)[idx] = make_short4(l0, l1, l2, l3);
  }
}

// ---------------------------------------------------------------------------
// Pack int32 mask [B,H,N,M] -> bitmask via wave ballot.
// ---------------------------------------------------------------------------
__global__ __launch_bounds__(256) void mask_pack(
    const int* __restrict__ mask, unsigned* __restrict__ pm) {
  const size_t total = (size_t)B_ * H_ * N_ * M_;
  const size_t stride = (size_t)gridDim.x * blockDim.x;
  const int lane = threadIdx.x & 63;
  for (size_t i = (size_t)blockIdx.x * blockDim.x + threadIdx.x; i < total;
       i += stride) {
    unsigned long long bal = __ballot(mask[i] != 0);
    if (lane == 0) *(unsigned long long*)(pm + (i >> 5)) = bal;
  }
}

// ---------------------------------------------------------------------------
// All three QKV GEMMs in one launch (grid 18 x 81). Split-bf16 MFMA,
// global_load_lds staging (unpadded [128][32] LDS rows = tid-linear dest).
// ---------------------------------------------------------------------------
__global__ __launch_bounds__(256) void qkv_all(
    const short* __restrict__ xsh, const short* __restrict__ xsl,
    const short* __restrict__ kxsh, const short* __restrict__ kxsl,
    const short* __restrict__ csh, const short* __restrict__ csl,
    const short* __restrict__ Wth, const short* __restrict__ Wtl,
    short* __restrict__ tqh, short* __restrict__ tql,
    short* __restrict__ tkh, short* __restrict__ tkl, short* __restrict__ tvt,
    short* __restrict__ kqh, short* __restrict__ kql,
    short* __restrict__ kkh, short* __restrict__ kkl, short* __restrict__ kvt,
    short* __restrict__ cqh, short* __restrict__ cql,
    short* __restrict__ ckh, short* __restrict__ ckl, short* __restrict__ cvt) {
  __shared__ __align__(16) short As_h[128 * 32], As_l[128 * 32];
  __shared__ __align__(16) short Bs_h[128 * 32], Bs_l[128 * 32];
  int flat = blockIdx.y * 18 + blockIdx.x;
  flat = xcd_swizzle(flat, 18 * 81);
  int by = flat / 18, bx = flat % 18;
  const short *Ahp, *Alp; int rowsPerB, totalRows, r0;
  short *qh, *ql, *kh, *kl, *vt;
  if (by < 64) {
    Ahp = xsh; Alp = xsl; rowsPerB = N_; totalRows = B_ * N_; r0 = by * 128;
    qh = tqh; ql = tql; kh = tkh; kl = tkl; vt = tvt;
  } else if (by < 80) {
    Ahp = kxsh; Alp = kxsl; rowsPerB = M_; totalRows = B_ * M_;
    r0 = (by - 64) * 128;
    qh = kqh; ql = kql; kh = kkh; kl = kkl; vt = kvt;
  } else {
    Ahp = csh; Alp = csl; rowsPerB = 1; totalRows = B_; r0 = 0;
    qh = cqh; ql = cql; kh = ckh; kl = ckl; vt = cvt;
  }
  const int c0 = bx * 128;
  const int tid = threadIdx.x;
  const int w = tid >> 6, ln = tid & 63, q = ln >> 4, l15 = ln & 15;
  const int wM = (w & 1) * 64, wN = (w >> 1) * 64;
  const f32x4 z = {0.f, 0.f, 0.f, 0.f};
  f32x4 acc[4][4];
  for (int i = 0; i < 4; i++)
    for (int j = 0; j < 4; j++) acc[i][j] = z;
  for (int k0 = 0; k0 < DIM_; k0 += 32) {
    for (int e = tid; e < 512; e += 256) {
      int row = e >> 2, c = e & 3;
      int ar = r0 + row; if (ar >= totalRows) ar = totalRows - 1;
      size_t ga = (size_t)ar * DIM_ + k0 + c * 8;
      size_t gb = (size_t)(c0 + row) * DIM_ + k0 + c * 8;
      gl16(Ahp + ga, As_h + e * 8);
      gl16(Alp + ga, As_l + e * 8);
      gl16(Wth + gb, Bs_h + e * 8);
      gl16(Wtl + gb, Bs_l + e * 8);
    }
    __syncthreads();
    bf16x8 ah[4], al[4], bhf[4], blf[4];
    for (int mt = 0; mt < 4; mt++) {
      int o = (wM + mt * 16 + l15) * 32 + q * 8;
      ah[mt] = *(const bf16x8*)(As_h + o);
      al[mt] = *(const bf16x8*)(As_l + o);
    }
    for (int nt = 0; nt < 4; nt++) {
      int o = (wN + nt * 16 + l15) * 32 + q * 8;
      bhf[nt] = *(const bf16x8*)(Bs_h + o);
      blf[nt] = *(const bf16x8*)(Bs_l + o);
    }
    for (int mt = 0; mt < 4; mt++)
      for (int nt = 0; nt < 4; nt++) {
        f32x4 cc = acc[mt][nt];
        cc = MFMA16(ah[mt], bhf[nt], cc);
        cc = MFMA16(ah[mt], blf[nt], cc);
        cc = MFMA16(al[mt], bhf[nt], cc);
        acc[mt][nt] = cc;
      }
    __syncthreads();
  }
  for (int mt = 0; mt < 4; mt++)
    for (int nt = 0; nt < 4; nt++)
      for (int r = 0; r < 4; r++) {
        int gr = r0 + wM + mt * 16 + q * 4 + r;
        if (gr >= totalRows) continue;
        int gc = c0 + wN + nt * 16 + l15;
        int which = gc / DIM_;
        int rem = gc - which * DIM_;
        int hh = rem >> 6, d = rem & 63;
        int b = gr / rowsPerB, n = gr - b * rowsPerB;
        float v = acc[mt][nt][r];
        short hi = f2bf(v);
        if (which == 2) {
          vt[(((size_t)b * H_ + hh) * 64 + d) * rowsPerB + n] = hi;
        } else {
          short lo = f2bf(v - bf2f(hi));
          size_t o = (((size_t)b * H_ + hh) * rowsPerB + n) * 64 + d;
          if (which == 0) { qh[o] = hi; ql[o] = lo; }
          else           { kh[o] = hi; kl[o] = lo; }
        }
      }
}

// ---------------------------------------------------------------------------
// All three output projections in one launch (grid 6 x 81).
// ---------------------------------------------------------------------------
__global__ __launch_bounds__(256) void proj_all(
    const short* __restrict__ amh, const short* __restrict__ aml,
    const short* __restrict__ kmh, const short* __restrict__ kml,
    const short* __restrict__ cmh, const short* __restrict__ cml,
    const short* __restrict__ Bth, const short* __restrict__ Btl,
    const float* __restrict__ bias, float* __restrict__ out0,
    float* __restrict__ out1, float* __restrict__ out2) {
  __shared__ __align__(16) short As_h[128 * 32], As_l[128 * 32];
  __shared__ __align__(16) short Bs_h[128 * 32], Bs_l[128 * 32];
  int flat = blockIdx.y * 6 + blockIdx.x;
  flat = xcd_swizzle(flat, 6 * 81);
  int by = flat / 6, bx = flat % 6;
  const short *Ahp, *Alp; int totalRows, r0; float* C;
  if (by < 64) { Ahp = amh; Alp = aml; totalRows = B_ * N_; r0 = by * 128; C = out0; }
  else if (by < 80) { Ahp = kmh; Alp = kml; totalRows = B_ * M_; r0 = (by - 64) * 128; C = out1; }
  else { Ahp = cmh; Alp = cml; totalRows = B_; r0 = 0; C = out2; }
  const int c0 = bx * 128;
  const int tid = threadIdx.x;
  const int w = tid >> 6, ln = tid & 63, q = ln >> 4, l15 = ln & 15;
  const int wM = (w & 1) * 64, wN = (w >> 1) * 64;
  const f32x4 z = {0.f, 0.f, 0.f, 0.f};
  f32x4 acc[4][4];
  for (int i = 0; i < 4; i++)
    for (int j = 0; j < 4; j++) acc[i][j] = z;
  for (int k0 = 0; k0 < DIM_; k0 += 32) {
    for (int e = tid; e < 512; e += 256) {
      int row = e >> 2, c = e & 3;
      int ar = r0 + row; if (ar >= totalRows) ar = totalRows - 1;
      size_t ga = (size_t)ar * DIM_ + k0 + c * 8;
      size_t gb = (size_t)(c0 + row) * DIM_ + k0 + c * 8;
      gl16(Ahp + ga, As_h + e * 8);
      gl16(Alp + ga, As_l + e * 8);
      gl16(Bth + gb, Bs_h + e * 8);
      gl16(Btl + gb, Bs_l + e * 8);
    }
    __syncthreads();
    bf16x8 ah[4], al[4], bhf[4], blf[4];
    for (int mt = 0; mt < 4; mt++) {
      int o = (wM + mt * 16 + l15) * 32 + q * 8;
      ah[mt] = *(const bf16x8*)(As_h + o);
      al[mt] = *(const bf16x8*)(As_l + o);
    }
    for (int nt = 0; nt < 4; nt++) {
      int o = (wN + nt * 16 + l15) * 32 + q * 8;
      bhf[nt] = *(const bf16x8*)(Bs_h + o);
      blf[nt] = *(const bf16x8*)(Bs_l + o);
    }
    for (int mt = 0; mt < 4; mt++)
      for (int nt = 0; nt < 4; nt++) {
        f32x4 cc = acc[mt][nt];
        cc = MFMA16(ah[mt], bhf[nt], cc);
        cc = MFMA16(ah[mt], blf[nt], cc);
        cc = MFMA16(al[mt], bhf[nt], cc);
        acc[mt][nt] = cc;
      }
    __syncthreads();
  }
  for (int mt = 0; mt < 4; mt++)
    for (int nt = 0; nt < 4; nt++)
      for (int r = 0; r < 4; r++) {
        int gr = r0 + wM + mt * 16 + q * 4 + r;
        if (gr >= totalRows) continue;
        int gc = c0 + wN + nt * 16 + l15;
        C[(size_t)gr * DIM_ + gc] = acc[mt][nt][r] + bias[gc];
      }
}

// ---------------------------------------------------------------------------
// Branch 1 (MFMA): per (b,h,32 n-rows), 512 threads / 8 waves.
// Stats phase fused in registers (1 LDS read + 1 write per element).
// ---------------------------------------------------------------------------
__global__ __launch_bounds__(512, 4) void branch1_mfma(
    const short* __restrict__ tqh, const short* __restrict__ tql,
    const short* __restrict__ kkh, const short* __restrict__ kkl,
    const short* __restrict__ kvt, const float* __restrict__ krd,
    const unsigned* __restrict__ pm, float* __restrict__ out3,
    short* __restrict__ amh, short* __restrict__ aml) {
  __shared__ __align__(16) float sc[32 * 520];  // 66560 B, aliased by P2h/P2l
  __shared__ unsigned mskw[512];                // 32 rows x 16 words
  __shared__ float inv1[32], inv2[32];
  short* P2h = (short*)sc;          // [32][520]
  short* P2l = P2h + 32 * 520;
  const int b = blockIdx.z, h = blockIdx.y, n0 = blockIdx.x * 32;
  const size_t bhi = (size_t)b * H_ + h;
  const int tid = threadIdx.x;
  const int w = tid >> 6, ln = tid & 63, q = ln >> 4, l15 = ln & 15;
  const float* krd0 = krd + bhi * M_ * N_;
  mskw[tid] = pm[(bhi * N_ + n0) * 16 + tid];
  // ---- QK^T: 32n x 512m, wave w -> ct in [4w, 4w+4) ----
  {
    bf16x8 ah[2][2], al[2][2];
    for (int mt = 0; mt < 2; mt++) {
      const short* ap = tqh + ((bhi * N_ + n0 + mt * 16 + l15) * D_ + q * 8);
      const short* ap2 = tql + ((bhi * N_ + n0 + mt * 16 + l15) * D_ + q * 8);
      ah[mt][0] = *(const bf16x8*)(ap);
      ah[mt][1] = *(const bf16x8*)(ap + 32);
      al[mt][0] = *(const bf16x8*)(ap2);
      al[mt][1] = *(const bf16x8*)(ap2 + 32);
    }
    for (int t = 0; t < 4; t++) {
      int ct = w * 4 + t;
      const short* bp = kkh + ((bhi * M_ + ct * 16 + l15) * D_ + q * 8);
      const short* bp2 = kkl + ((bhi * M_ + ct * 16 + l15) * D_ + q * 8);
      bf16x8 bh0 = *(const bf16x8*)(bp);
      bf16x8 bh1 = *(const bf16x8*)(bp + 32);
      bf16x8 bl0 = *(const bf16x8*)(bp2);
      bf16x8 bl1 = *(const bf16x8*)(bp2 + 32);
      for (int mt = 0; mt < 2; mt++) {
        f32x4 a = {0.f, 0.f, 0.f, 0.f};
        a = MFMA16(ah[mt][0], bh0, a); a = MFMA16(ah[mt][1], bh1, a);
        a = MFMA16(ah[mt][0], bl0, a); a = MFMA16(ah[mt][1], bl1, a);
        a = MFMA16(al[mt][0], bh0, a); a = MFMA16(al[mt][1], bh1, a);
        for (int r = 0; r < 4; r++) {
          int row = mt * 16 + q * 4 + r;
          sc[row * 520 + ((ct * 16 + l15) ^ ((row >> 2) & 7))] = a[r];
        }
      }
    }
  }
  // ---- prefetch krd for P-build (latency hides under stats phase) ----
  const int pi = tid & 31, pg = tid >> 5;
  float kr[32];
#pragma unroll
  for (int t = 0; t < 32; t++)
    kr[t] = __builtin_nontemporal_load(
        krd0 + (size_t)(pg * 32 + t) * N_ + n0 + pi);
  __syncthreads();
  // ---- mask + scale + stats fused in registers; sc ends holding e2 ----
  {
    int i = tid >> 4, jl = tid & 15;
    int sw = (i >> 2) & 7;
    float* scr = sc + i * 520;
    const unsigned* mrow = mskw + i * 16;
    float dv[32];
    float mx = -INFINITY;
#pragma unroll
    for (int t = 0; t < 32; t++) {
      int j = jl + 16 * t;
      float d = scr[j ^ sw];
      d = ((mrow[j >> 5] >> (j & 31)) & 1) ? NEG_ : d * SCALE_;
      dv[t] = d;
      mx = fmaxf(mx, d);
    }
    for (int o = 8; o >= 1; o >>= 1) mx = fmaxf(mx, __shfl_xor(mx, o, 16));
    float s1 = 0.f, s2 = 0.f;
#pragma unroll
    for (int t = 0; t < 32; t++) {
      int j = jl + 16 * t;
      float e2 = __expf(dv[t] - mx);
      scr[j ^ sw] = e2;
      float x2 = e2 * e2, x4 = x2 * x2, x8 = x4 * x4, x16 = x8 * x8;
      s1 += x16 * x8;   // e2^24
      s2 += e2;
    }
    for (int o = 8; o >= 1; o >>= 1) {
      s1 += __shfl_xor(s1, o, 16);
      s2 += __shfl_xor(s2, o, 16);
    }
    if (jl == 0) { inv1[i] = 1.f / s1; inv2[i] = 1.f / s2; }
  }
  __syncthreads();
  // ---- P build: out3 write + P2 hi/lo (overlay sc via register staging) ----
  {
    float rv[32];
    int sw2 = (pi >> 2) & 7;
#pragma unroll
    for (int t = 0; t < 32; t++)
      rv[t] = sc[pi * 520 + ((pg * 32 + t) ^ sw2)];
    __syncthreads();
    float v1 = inv1[pi], v2 = inv2[pi];
    float* o3 = out3 + bhi * M_ * N_ + n0 + pi;
#pragma unroll
    for (int t = 0; t < 32; t += 2) {
      int j = pg * 32 + t;
      float e2a = rv[t], e2b = rv[t + 1];
      float a2 = e2a * e2a, a4 = a2 * a2, a8 = a4 * a4, a16 = a8 * a8;
      float b2 = e2b * e2b, b4 = b2 * b2, b8 = b4 * b4, b16 = b8 * b8;
      __builtin_nontemporal_store(a16 * a8 * v1 * kr[t], o3 + (size_t)j * N_);
      __builtin_nontemporal_store(b16 * b8 * v1 * kr[t + 1],
                                  o3 + (size_t)(j + 1) * N_);
      float p0 = e2a * v2 * kr[t];
      float p1 = e2b * v2 * kr[t + 1];
      short h0 = f2bf(p0), h1 = f2bf(p1);
      short lo0 = f2bf(p0 - bf2f(h0)), lo1 = f2bf(p1 - bf2f(h1));
      *(short2*)(P2h + pi * 520 + j) = make_short2(h0, h1);
      *(short2*)(P2l + pi * 520 + j) = make_short2(lo0, lo1);
    }
  }
  __syncthreads();
  // ---- PV: wave w -> (n-half, d-chunk) ----
  {
    const int dc = w & 3, nh = w >> 2;
    f32x4 o0 = {0.f, 0.f, 0.f, 0.f}, o1 = {0.f, 0.f, 0.f, 0.f};
    const short* vbase = kvt + ((bhi * 64 + dc * 16 + l15) * (size_t)M_ + q * 8);
    const short* ph = P2h + (nh * 16 + l15) * 520 + q * 8;
    const short* pl = P2l + (nh * 16 + l15) * 520 + q * 8;
    for (int kc = 0; kc < 16; kc += 2) {
      bf16x8 pa0 = *(const bf16x8*)(ph + kc * 32);
      bf16x8 pl0 = *(const bf16x8*)(pl + kc * 32);
      bf16x8 bv0 = *(const bf16x8*)(vbase + kc * 32);
      o0 = MFMA16(pa0, bv0, o0);
      o0 = MFMA16(pl0, bv0, o0);
      bf16x8 pa1 = *(const bf16x8*)(ph + (kc + 1) * 32);
      bf16x8 pl1 = *(const bf16x8*)(pl + (kc + 1) * 32);
      bf16x8 bv1 = *(const bf16x8*)(vbase + (kc + 1) * 32);
      o1 = MFMA16(pa1, bv1, o1);
      o1 = MFMA16(pl1, bv1, o1);
    }
    o0 += o1;
    for (int r = 0; r < 4; r++) {
      float v = o0[r];
      short hi = f2bf(v), lo = f2bf(v - bf2f(hi));
      size_t o = ((size_t)b * N_ + n0 + nh * 16 + q * 4 + r) * DIM_ +
                 h * 64 + dc * 16 + l15;
      amh[o] = hi; aml[o] = lo;
    }
  }
}

// ---------------------------------------------------------------------------
// Branch 2 (MFMA, flash, split-8): per (b,h,32 m-rows, n-eighth = 256).
// krd staged into LDS via global_load_lds at iteration top (2 barriers of
// latency cover). Unnormalized partials; b2_combine merges.
// ---------------------------------------------------------------------------
__global__ __launch_bounds__(256) void branch2_mfma(
    const short* __restrict__ kqh, const short* __restrict__ kql,
    const short* __restrict__ tkh, const short* __restrict__ tkl,
    const short* __restrict__ tvt, const float* __restrict__ krd,
    const unsigned* __restrict__ pm, float* __restrict__ pO,
    float* __restrict__ pML) {
  __shared__ __align__(16) float sc[32 * 136];  // 17408 B, aliased by P2h/P2l
  __shared__ __align__(16) float krdL[32 * 128];  // 16 KB
  __shared__ unsigned mskw[128];
  __shared__ float rowM[32], rowL[32], alph[32];
  short* P2h = (short*)sc;          // [32][136]
  short* P2l = P2h + 32 * 136;
  const int b = blockIdx.z, h = blockIdx.y;
  const int mblk = blockIdx.x >> 3, split = blockIdx.x & 7;
  const int m0 = mblk * 32;
  const size_t bhi = (size_t)b * H_ + h;
  const int pidx = ((int)bhi * 16 + mblk) * NSPLIT_ + split;
  const int tid = threadIdx.x;
  const int w = tid >> 6, ln = tid & 63, q = ln >> 4, l15 = ln & 15;
  const float* krd0 = krd + (bhi * M_ + m0) * N_;
  const int mword = mblk;
  bf16x8 Ah[2][2], Al[2][2];
  for (int mt = 0; mt < 2; mt++)
    for (int kc = 0; kc < 2; kc++) {
      size_t o = (bhi * M_ + m0 + mt * 16 + l15) * D_ + kc * 32 + q * 8;
      Ah[mt][kc] = *(const bf16x8*)(kqh + o);
      Al[mt][kc] = *(const bf16x8*)(kql + o);
    }
  if (tid < 32) { rowM[tid] = -INFINITY; rowL[tid] = 0.f; }
  const f32x4 z = {0.f, 0.f, 0.f, 0.f};
  f32x4 oa[2]; oa[0] = z; oa[1] = z;
  __syncthreads();
  const int nbeg = split * (N_ / NSPLIT_);
  for (int n0 = nbeg; n0 < nbeg + N_ / NSPLIT_; n0 += 128) {
    if (tid < 128) mskw[tid] = pm[(bhi * N_ + n0 + tid) * 16 + mword];
    // async krd tile [32 m][128 n] -> LDS (consumed 2 barriers later)
    for (int e = tid; e < 1024; e += 256) {
      int row = e >> 5, c = e & 31;
      gl16(krd0 + (size_t)row * N_ + n0 + c * 4, krdL + e * 4);
    }
    for (int t = 0; t < 2; t++) {  // QK: wave w -> ct = 2w+t
      int ct = w * 2 + t;
      const short* bp = tkh + ((bhi * N_ + n0 + ct * 16 + l15) * D_ + q * 8);
      const short* bp2 = tkl + ((bhi * N_ + n0 + ct * 16 + l15) * D_ + q * 8);
      bf16x8 bh0 = *(const bf16x8*)(bp), bh1 = *(const bf16x8*)(bp + 32);
      bf16x8 bl0 = *(const bf16x8*)(bp2), bl1 = *(const bf16x8*)(bp2 + 32);
      for (int mt = 0; mt < 2; mt++) {
        f32x4 a = {0.f, 0.f, 0.f, 0.f};
        a = MFMA16(Ah[mt][0], bh0, a); a = MFMA16(Ah[mt][1], bh1, a);
        a = MFMA16(Ah[mt][0], bl0, a); a = MFMA16(Ah[mt][1], bl1, a);
        a = MFMA16(Al[mt][0], bh0, a); a = MFMA16(Al[mt][1], bh1, a);
        for (int r = 0; r < 4; r++)
          sc[(mt * 16 + q * 4 + r) * 136 + ct * 16 + l15] = a[r];
      }
    }
    __syncthreads();
    {  // online softmax: 8 threads/row
      int i = tid >> 3, jl = tid & 7;
      float mx = -INFINITY;
      for (int j = jl; j < 128; j += 8) {
        float s = sc[i * 136 + j];
        s = ((mskw[j] >> i) & 1) ? NEG_ : s * SCALE_;
        sc[i * 136 + j] = s;
        mx = fmaxf(mx, s);
      }
      for (int o = 4; o >= 1; o >>= 1) mx = fmaxf(mx, __shfl_xor(mx, o, 8));
      float mold = rowM[i];
      float mnew = fmaxf(mold, mx);
      float sum = 0.f;
      for (int j = jl; j < 128; j += 8) {
        float p = __expf(sc[i * 136 + j] - mnew);
        sc[i * 136 + j] = p;
        sum += p;
      }
      for (int o = 4; o >= 1; o >>= 1) sum += __shfl_xor(sum, o, 8);
      if (jl == 0) {
        float al = (mold == -INFINITY) ? 0.f : __expf(mold - mnew);
        alph[i] = al;
        rowL[i] = rowL[i] * al + sum;
        rowM[i] = mnew;
      }
    }
    __syncthreads();
    {  // P2 = p * krd(LDS), hi/lo (overlay sc via register staging)
      float rv[16];
      const int j = tid & 127;
      const int ib = tid >> 7;
#pragma unroll
      for (int t = 0; t < 16; t++) rv[t] = sc[(ib + 2 * t) * 136 + j];
      __syncthreads();
#pragma unroll
      for (int t = 0; t < 16; t++) {
        int i = ib + 2 * t;
        float p2 = rv[t] * krdL[i * 128 + j];
        short hi = f2bf(p2), lo = f2bf(p2 - bf2f(hi));
        P2h[i * 136 + j] = hi;
        P2l[i * 136 + j] = lo;
      }
    }
    __syncthreads();
    {  // PV accumulate, wave w -> dc = w
      for (int mt = 0; mt < 2; mt++) {
        f32x4 t = oa[mt];
        for (int r = 0; r < 4; r++) t[r] *= alph[mt * 16 + q * 4 + r];
        for (int kc = 0; kc < 4; kc++) {
          bf16x8 pa = *(const bf16x8*)(P2h + (mt * 16 + l15) * 136 + kc * 32 + q * 8);
          bf16x8 pl = *(const bf16x8*)(P2l + (mt * 16 + l15) * 136 + kc * 32 + q * 8);
          bf16x8 bv = *(const bf16x8*)(tvt + ((bhi * 64 + w * 16 + l15) * (size_t)N_ + n0 + kc * 32 + q * 8));
          t = MFMA16(pa, bv, t);
          t = MFMA16(pl, bv, t);
        }
        oa[mt] = t;
      }
    }
    __syncthreads();
  }
  // write unnormalized partials
  float* po = pO + (size_t)pidx * 2048;
  for (int mt = 0; mt < 2; mt++)
    for (int r = 0; r < 4; r++) {
      int row = mt * 16 + q * 4 + r;
      po[row * 64 + w * 16 + l15] = oa[mt][r];
    }
  if (tid < 32) {
    pML[(size_t)pidx * 64 + tid] = rowM[tid];
    pML[(size_t)pidx * 64 + 32 + tid] = rowL[tid];
  }
}

// ---------------------------------------------------------------------------
// Flash merge of branch2's NSPLIT partials -> km hi/lo bf16.
// ---------------------------------------------------------------------------
__global__ __launch_bounds__(256) void b2_combine(
    const float* __restrict__ pO, const float* __restrict__ pML,
    short* __restrict__ kmh, short* __restrict__ kml) {
  const int mblk = blockIdx.x, h = blockIdx.y, b = blockIdx.z;
  const size_t bhi = (size_t)b * H_ + h;
  const int base = ((int)bhi * 16 + mblk) * NSPLIT_;
  __shared__ float mS[NSPLIT_][32], lS[NSPLIT_][32], wgt[NSPLIT_][32], invL[32];
  const int tid = threadIdx.x;
  {
    int s = tid >> 5, r = tid & 31;  // 256 threads = exactly 8x32
    mS[s][r] = pML[(size_t)(base + s) * 64 + r];
    lS[s][r] = pML[(size_t)(base + s) * 64 + 32 + r];
  }
  __syncthreads();
  if (tid < 32) {
    float Mv = mS[0][tid];
    for (int s = 1; s < NSPLIT_; s++) Mv = fmaxf(Mv, mS[s][tid]);
    float L = 0.f;
    for (int s = 0; s < NSPLIT_; s++) {
      float wv = __expf(mS[s][tid] - Mv);
      wgt[s][tid] = wv;
      L += lS[s][tid] * wv;
    }
    invL[tid] = 1.f / L;
  }
  __syncthreads();
  const int row = tid >> 3, c0 = (tid & 7) * 8;
  float acc[8] = {0, 0, 0, 0, 0, 0, 0, 0};
  for (int s = 0; s < NSPLIT_; s++) {
    float wv = wgt[s][row];
    const float* src = pO + (size_t)(base + s) * 2048 + row * 64 + c0;
    float4 a = *(const float4*)(src);
    float4 bq = *(const float4*)(src + 4);
    acc[0] += a.x * wv;  acc[1] += a.y * wv;
    acc[2] += a.z * wv;  acc[3] += a.w * wv;
    acc[4] += bq.x * wv; acc[5] += bq.y * wv;
    acc[6] += bq.z * wv; acc[7] += bq.w * wv;
  }
  float il = invL[row];
  size_t o = ((size_t)b * M_ + mblk * 32 + row) * DIM_ + h * 64 + c0;
#pragma unroll
  for (int e = 0; e < 8; e++) {
    float v = acc[e] * il;
    short hi = f2bf(v), lo = f2bf(v - bf2f(hi));
    kmh[o + e] = hi; kml[o + e] = lo;
  }
}

// ---------------------------------------------------------------------------
// Branch 3: cluster query per (b,h), vector math from hi/lo inputs.
// ---------------------------------------------------------------------------
__global__ __launch_bounds__(256) void branch3_k(
    const short* __restrict__ cqh, const short* __restrict__ cql,
    const short* __restrict__ kkh, const short* __restrict__ kkl,
    const short* __restrict__ kvt, const unsigned* __restrict__ pm,
    short* __restrict__ cmh, short* __restrict__ cml) {
  const int h = blockIdx.x, b = blockIdx.y;
  __shared__ float qv[64];
  __shared__ float p[512];
  __shared__ float wr1[4], wr2[4];
  __shared__ float ored[4][64];
  const size_t bhi = (size_t)b * H_ + h;
  const int tid = threadIdx.x;
  if (tid < 64) qv[tid] = bf2f(cqh[bhi * 64 + tid]) + bf2f(cql[bhi * 64 + tid]);
  __syncthreads();
  const unsigned* m0p = pm + bhi * N_ * 16;  // row n = 0
  for (int j = tid; j < 512; j += 256) {
    float acc = 0;
    for (int kk = 0; kk < 64; kk++)
      acc += qv[kk] * (bf2f(kkh[(bhi * M_ + j) * 64 + kk]) +
                       bf2f(kkl[(bhi * M_ + j) * 64 + kk]));
    acc *= SCALE_;
    if ((m0p[j >> 5] >> (j & 31)) & 1) acc = NEG_;
    p[j] = acc;
  }
  __syncthreads();
  float mx = fmaxf(p[tid], p[tid + 256]);
  for (int o = 32; o >= 1; o >>= 1) mx = fmaxf(mx, __shfl_xor(mx, o, 64));
  if ((tid & 63) == 0) wr1[tid >> 6] = mx;
  __syncthreads();
  mx = fmaxf(fmaxf(wr1[0], wr1[1]), fmaxf(wr1[2], wr1[3]));
  float e0 = __expf(p[tid] - mx), e1 = __expf(p[tid + 256] - mx);
  float s = e0 + e1;
  for (int o = 32; o >= 1; o >>= 1) s += __shfl_xor(s, o, 64);
  p[tid] = e0; p[tid + 256] = e1;
  if ((tid & 63) == 0) wr2[tid >> 6] = s;
  __syncthreads();
  float invS = 1.f / (wr2[0] + wr2[1] + wr2[2] + wr2[3]);
  int dd = tid & 63, gg = tid >> 6;
  float o = 0;
  for (int j = gg; j < 512; j += 4)
    o += p[j] * bf2f(kvt[(bhi * 64 + dd) * (size_t)M_ + j]);
  ored[gg][dd] = o;
  __syncthreads();
  if (gg == 0) {
    float r = (ored[0][dd] + ored[1][dd] + ored[2][dd] + ored[3][dd]) * invS;
    short hi = f2bf(r), lo = f2bf(r - bf2f(hi));
    cmh[(size_t)b * DIM_ + h * 64 + dd] = hi;
    cml[(size_t)b * DIM_ + h * 64 + dd] = lo;
  }
}

// ---------------------------------------------------------------------------
extern "C" void kernel_launch(void* const* d_in, const int* in_sizes, int n_in,
                              void* d_out, int out_size, void* d_ws,
                              size_t ws_size, hipStream_t stream) {
  const float* x = (const float*)d_in[0];
  const float* kx = (const float*)d_in[1];
  const float* krd = (const float*)d_in[2];
  const float* clst = (const float*)d_in[3];
  const int* mask = (const int*)d_in[4];
  const float* Wqkv = (const float*)d_in[5];
  const float* Wout = (const float*)d_in[6];
  const float* bout = (const float*)d_in[7];

  short* p = (short*)d_ws;
  auto alloc = [&](size_t n) { short* r = p; p += n; return r; };
  short* Wq_h = alloc(2304ull * 768); short* Wq_l = alloc(2304ull * 768);
  short* Wo_h = alloc(768ull * 768);  short* Wo_l = alloc(768ull * 768);
  short* tq_h = alloc(6291456); short* tq_l = alloc(6291456);
  short* tk_h = alloc(6291456); short* tk_l = alloc(6291456);
  short* tv_t = alloc(6291456);
  short* kq_h = alloc(1572864); short* kq_l = alloc(1572864);
  short* kk_h = alloc(1572864); short* kk_l = alloc(1572864);
  short* kv_t = alloc(1572864);
  short* cq_h = alloc(3072); short* cq_l = alloc(3072);
  short* ck_h = alloc(3072); short* ck_l = alloc(3072);
  short* cv_t = alloc(3072);
  short* am_h = alloc(6291456); short* am_l = alloc(6291456);
  short* km_h = alloc(1572864); short* km_l = alloc(1572864);
  short* cm_h = alloc(3072); short* cm_l = alloc(3072);

  float* out0 = (float*)d_out;        // [B,N,768]
  float* out1 = out0 + 6291456;       // [B,M,768]
  float* out2 = out1 + 1572864;       // [B,1,768]
  float* out3 = out2 + 3072;          // [B,H,M,N] (50.33M floats)

  wsplit_all<<<dim3(96, 24), 256, 0, stream>>>(Wqkv, Wout, Wq_h, Wq_l,
                                               Wo_h, Wo_l);

  // Pre-split activations; buffers alias the dead-until-branch am/km/cm space.
  short* xs_h = am_h, *xs_l = am_l;     // [B*N,768]
  short* kxs_h = km_h, *kxs_l = km_l;   // [B*M,768]
  short* cs_h = cm_h, *cs_l = cm_l;     // [B,768]
  fsplit_all<<<dim3(2048), 256, 0, stream>>>(x, kx, clst, xs_h, xs_l,
                                             kxs_h, kxs_l, cs_h, cs_l);

  qkv_all<<<dim3(18, 81), 256, 0, stream>>>(
      xs_h, xs_l, kxs_h, kxs_l, cs_h, cs_l, Wq_h, Wq_l,
      tq_h, tq_l, tk_h, tk_l, tv_t,
      kq_h, kq_l, kk_h, kk_l, kv_t,
      cq_h, cq_l, ck_h, ck_l, cv_t);

  // Wq dead after qkv; reuse for packed mask (6.29 MB < 7.08 MB).
  unsigned* pmask = (unsigned*)Wq_h;
  mask_pack<<<dim3(2048), 256, 0, stream>>>(mask, pmask);

  // Branch2 first (its partials borrow the not-yet-written out3 region, and
  // its krd stream warms L3 for branch1).
  float* pO = out3;                       // 6144 x 2048 f32 = 50.3 MB
  float* pML = out3 + 12582912;           // 6144 x 64 f32
  branch2_mfma<<<dim3((M_ / 32) * NSPLIT_, H_, B_), 256, 0, stream>>>(
      kq_h, kq_l, tk_h, tk_l, tv_t, krd, pmask, pO, pML);
  b2_combine<<<dim3(M_ / 32, H_, B_), 256, 0, stream>>>(pO, pML, km_h, km_l);

  branch1_mfma<<<dim3(N_ / 32, H_, B_), 512, 0, stream>>>(
      tq_h, tq_l, kk_h, kk_l, kv_t, krd, pmask, out3, am_h, am_l);

  branch3_k<<<dim3(H_, B_), 256, 0, stream>>>(cq_h, cq_l, kk_h, kk_l, kv_t,
                                              pmask, cm_h, cm_l);

  proj_all<<<dim3(6, 81), 256, 0, stream>>>(am_h, am_l, km_h, km_l, cm_h, cm_l,
                                            Wo_h, Wo_l, bout, out0, out1, out2);
}